// Round 1
// baseline (1811.657 us; speedup 1.0000x reference)
//
#include <hip/hip_runtime.h>
#include <hip/hip_bf16.h>
#include <math.h>

#define T_TOK 1024
#define HIDDEN 2880
#define HD 64
#define NH 64
#define NKV 8
#define SW 128
#define QKV_DIM 5120   // HD*(NH+2*NKV)
#define ATTN_DIM 4096  // NH*HD

// ---------------- RoPE table (1024 x 32) ----------------
__global__ void rope_table_kernel(float* __restrict__ cosT, float* __restrict__ sinT) {
    int gid = blockIdx.x * 256 + threadIdx.x;   // < 1024*32
    int i = gid & 31;
    int t = gid >> 5;
    const double d_half = 32.0;
    double freq = pow(150000.0, (double)i / 32.0);
    double lowd  = d_half * log(4096.0 / (32.0 * 2.0 * M_PI)) / log(150000.0);
    double highd = d_half * log(4096.0 / (2.0 * M_PI)) / log(150000.0);
    double ramp = ((double)i - lowd) / (highd - lowd);
    ramp = fmin(fmax(ramp, 0.0), 1.0);
    double m = 1.0 - ramp;
    double inv_freq = (1.0 / (32.0 * freq)) * (1.0 - m) + (1.0 / freq) * m;
    float phase = (float)t * (float)inv_freq;    // fp32 multiply like numpy
    double conc = 0.1 * log(32.0) + 1.0;
    cosT[gid] = (float)(cos((double)phase) * conc);
    sinT[gid] = (float)(sin((double)phase) * conc);
}

// ---------------- RMSNorm: t = x * rsqrt(mean(x^2)+1e-5) * scale ----------------
__global__ __launch_bounds__(256) void rmsnorm_kernel(const float* __restrict__ x,
                                                      const float* __restrict__ scale,
                                                      float* __restrict__ t) {
    const int row = blockIdx.x;
    const int tid = threadIdx.x;
    const float4* xr = (const float4*)(x + (size_t)row * HIDDEN);
    float4 v[3];
    float ss = 0.f;
    int cnt = 0;
    for (int i = tid; i < HIDDEN / 4; i += 256) {
        float4 a = xr[i];
        v[cnt++] = a;
        ss += a.x * a.x + a.y * a.y + a.z * a.z + a.w * a.w;
    }
    #pragma unroll
    for (int off = 32; off; off >>= 1) ss += __shfl_xor(ss, off);
    __shared__ float red[4];
    if ((tid & 63) == 0) red[tid >> 6] = ss;
    __syncthreads();
    float total = red[0] + red[1] + red[2] + red[3];
    float inv = rsqrtf(total / (float)HIDDEN + 1e-5f);
    const float4* sc = (const float4*)scale;
    float4* tr = (float4*)(t + (size_t)row * HIDDEN);
    cnt = 0;
    for (int i = tid; i < HIDDEN / 4; i += 256) {
        float4 a = v[cnt++];
        float4 s4 = sc[i];
        float4 o;
        o.x = a.x * inv * s4.x; o.y = a.y * inv * s4.y;
        o.z = a.z * inv * s4.z; o.w = a.w * inv * s4.w;
        tr[i] = o;
    }
}

// ---------------- GEMM: C[M][N] = A[M][K] * B[N][K]^T + bias[N] ----------------
#define BM 64
#define BN 128
#define BK 16
__global__ __launch_bounds__(128) void gemm_bt_kernel(const float* __restrict__ A,
                                                      const float* __restrict__ B,
                                                      const float* __restrict__ bias,
                                                      float* __restrict__ C,
                                                      int M, int N, int K) {
    __shared__ __align__(16) float As[BK][BM];
    __shared__ __align__(16) float Bs[BK][BN];
    const int tid = threadIdx.x;
    const int m0 = blockIdx.x * BM;
    const int n0 = blockIdx.y * BN;
    const int tx = tid & 15;   // 16 col groups
    const int ty = tid >> 4;   // 8 row groups

    float acc[8][8];
    #pragma unroll
    for (int i = 0; i < 8; ++i)
        #pragma unroll
        for (int j = 0; j < 8; ++j) acc[i][j] = 0.f;

    for (int t0 = 0; t0 < K; t0 += BK) {
        __syncthreads();
        #pragma unroll
        for (int i = 0; i < 2; ++i) {   // A: 64x16 = 256 f4 / 128 thr
            int idx = tid + i * 128;
            int r = idx >> 2, c4 = idx & 3;
            float4 v = *(const float4*)(A + (size_t)(m0 + r) * K + t0 + c4 * 4);
            As[c4 * 4 + 0][r] = v.x; As[c4 * 4 + 1][r] = v.y;
            As[c4 * 4 + 2][r] = v.z; As[c4 * 4 + 3][r] = v.w;
        }
        #pragma unroll
        for (int i = 0; i < 4; ++i) {   // B: 128x16 = 512 f4 / 128 thr
            int idx = tid + i * 128;
            int r = idx >> 2, c4 = idx & 3;
            int gn = n0 + r;
            float4 v = make_float4(0.f, 0.f, 0.f, 0.f);
            if (gn < N) v = *(const float4*)(B + (size_t)gn * K + t0 + c4 * 4);
            Bs[c4 * 4 + 0][r] = v.x; Bs[c4 * 4 + 1][r] = v.y;
            Bs[c4 * 4 + 2][r] = v.z; Bs[c4 * 4 + 3][r] = v.w;
        }
        __syncthreads();
        #pragma unroll
        for (int kk = 0; kk < BK; ++kk) {
            float a[8], b[8];
            *(float4*)&a[0] = *(const float4*)&As[kk][ty * 8];
            *(float4*)&a[4] = *(const float4*)&As[kk][ty * 8 + 4];
            *(float4*)&b[0] = *(const float4*)&Bs[kk][tx * 4];
            *(float4*)&b[4] = *(const float4*)&Bs[kk][64 + tx * 4];
            #pragma unroll
            for (int i = 0; i < 8; ++i)
                #pragma unroll
                for (int j = 0; j < 8; ++j)
                    acc[i][j] += a[i] * b[j];
        }
    }

    const int n_lo = n0 + tx * 4;
    const int n_hi = n0 + 64 + tx * 4;
    float4 b_lo = make_float4(0.f, 0.f, 0.f, 0.f), b_hi = b_lo;
    if (n_lo < N) b_lo = *(const float4*)(bias + n_lo);
    if (n_hi < N) b_hi = *(const float4*)(bias + n_hi);
    #pragma unroll
    for (int i = 0; i < 8; ++i) {
        int gm = m0 + ty * 8 + i;
        if (n_lo < N) {
            float4 o;
            o.x = acc[i][0] + b_lo.x; o.y = acc[i][1] + b_lo.y;
            o.z = acc[i][2] + b_lo.z; o.w = acc[i][3] + b_lo.w;
            *(float4*)(C + (size_t)gm * N + n_lo) = o;
        }
        if (n_hi < N) {
            float4 o;
            o.x = acc[i][4] + b_hi.x; o.y = acc[i][5] + b_hi.y;
            o.z = acc[i][6] + b_hi.z; o.w = acc[i][7] + b_hi.w;
            *(float4*)(C + (size_t)gm * N + n_hi) = o;
        }
    }
}

// ---------------- RoPE apply (in-place on qkv: q heads 0..63, k heads 64..71) ----------------
__global__ __launch_bounds__(256) void rope_apply_kernel(float* __restrict__ qkv,
                                                         const float* __restrict__ cosT,
                                                         const float* __restrict__ sinT) {
    int gid = blockIdx.x * 256 + threadIdx.x;   // < 1024*72*32
    int i = gid & 31;
    int head = (gid >> 5) % 72;
    int t = gid / (72 * 32);
    size_t base = (size_t)t * QKV_DIM + (head < 64 ? head * 64 : ATTN_DIM + (head - 64) * 64);
    float x1 = qkv[base + i], x2 = qkv[base + 32 + i];
    float c = cosT[t * 32 + i], s = sinT[t * 32 + i];
    qkv[base + i]      = x1 * c - x2 * s;
    qkv[base + 32 + i] = x2 * c + x1 * s;
}

// ---------------- Sliding-window attention with sink ----------------
// block = (q, g): 256 threads = 4 waves, each wave does 2 heads of the 8 in group g.
__global__ __launch_bounds__(256) void attn_kernel(const float* __restrict__ qkv,
                                                   const float* __restrict__ sinks,
                                                   float* __restrict__ attn) {
    __shared__ __align__(16) float K_lds[128][65];
    __shared__ __align__(16) float V_lds[128][64];
    __shared__ __align__(16) float q_s[8][64];
    __shared__ float w_lds[4][128];
    const int q = blockIdx.x, g = blockIdx.y;
    const int tid = threadIdx.x;
    const int lane = tid & 63, w = tid >> 6;
    const int s = (q - (SW - 1)) > 0 ? (q - (SW - 1)) : 0;
    const int C = q - s + 1;   // 1..128 valid keys

    for (int idx = tid; idx < 8 * 64; idx += 256) {
        int hh = idx >> 6, d = idx & 63;
        q_s[hh][d] = qkv[(size_t)q * QKV_DIM + (g * 8 + hh) * 64 + d];
    }
    for (int idx = tid; idx < C * 16; idx += 256) {
        int r = idx >> 4, c4 = idx & 15;
        const float* krow = qkv + (size_t)(s + r) * QKV_DIM + ATTN_DIM + g * 64 + c4 * 4;
        float4 kv = *(const float4*)krow;
        K_lds[r][c4 * 4 + 0] = kv.x; K_lds[r][c4 * 4 + 1] = kv.y;
        K_lds[r][c4 * 4 + 2] = kv.z; K_lds[r][c4 * 4 + 3] = kv.w;
        float4 vv = *(const float4*)(krow + NKV * 64);
        *(float4*)&V_lds[r][c4 * 4] = vv;
    }
    __syncthreads();

    const float sm_scale = 0.125f;
    for (int hh2 = 0; hh2 < 2; ++hh2) {
        const int hh = w * 2 + hh2;
        const int h = g * 8 + hh;
        float acc0 = 0.f, acc1 = 0.f;
        #pragma unroll 8
        for (int d = 0; d < 64; ++d) {
            float qd = q_s[hh][d];
            acc0 += qd * K_lds[lane][d];
            acc1 += qd * K_lds[lane + 64][d];
        }
        float l0 = (lane < C) ? acc0 * sm_scale : -INFINITY;
        float l1 = (lane + 64 < C) ? acc1 * sm_scale : -INFINITY;
        float sink = sinks[h];
        float mx = fmaxf(fmaxf(l0, l1), sink);
        #pragma unroll
        for (int off = 32; off; off >>= 1) mx = fmaxf(mx, __shfl_xor(mx, off));
        float e0 = expf(l0 - mx), e1 = expf(l1 - mx);
        float sum = e0 + e1;
        #pragma unroll
        for (int off = 32; off; off >>= 1) sum += __shfl_xor(sum, off);
        float inv = 1.f / (sum + expf(sink - mx));
        w_lds[w][lane] = e0 * inv;
        w_lds[w][lane + 64] = e1 * inv;
        __syncthreads();
        float out = 0.f;
        for (int r = 0; r < C; ++r) out += w_lds[w][r] * V_lds[r][lane];
        attn[(size_t)q * ATTN_DIM + h * 64 + lane] = out;
        __syncthreads();
    }
}

extern "C" void kernel_launch(void* const* d_in, const int* in_sizes, int n_in,
                              void* d_out, int out_size, void* d_ws, size_t ws_size,
                              hipStream_t stream) {
    const float* x          = (const float*)d_in[0];
    const float* norm_scale = (const float*)d_in[1];
    const float* qkv_w      = (const float*)d_in[2];
    const float* qkv_b      = (const float*)d_in[3];
    const float* out_w      = (const float*)d_in[4];
    const float* out_b      = (const float*)d_in[5];
    const float* sinks      = (const float*)d_in[6];
    float* out = (float*)d_out;

    float* ws = (float*)d_ws;
    float* t_buf   = ws;                                    // 1024*2880
    float* qkv_buf = t_buf + (size_t)T_TOK * HIDDEN;        // 1024*5120
    float* attn_buf = qkv_buf + (size_t)T_TOK * QKV_DIM;    // 1024*4096
    float* cosT = attn_buf + (size_t)T_TOK * ATTN_DIM;      // 1024*32
    float* sinT = cosT + T_TOK * 32;                        // 1024*32

    rope_table_kernel<<<(T_TOK * 32) / 256, 256, 0, stream>>>(cosT, sinT);
    rmsnorm_kernel<<<T_TOK, 256, 0, stream>>>(x, norm_scale, t_buf);
    gemm_bt_kernel<<<dim3(T_TOK / BM, (QKV_DIM + BN - 1) / BN), 128, 0, stream>>>(
        t_buf, qkv_w, qkv_b, qkv_buf, T_TOK, QKV_DIM, HIDDEN);
    rope_apply_kernel<<<(T_TOK * 72 * 32) / 256, 256, 0, stream>>>(qkv_buf, cosT, sinT);
    attn_kernel<<<dim3(T_TOK, NKV), 256, 0, stream>>>(qkv_buf, sinks, attn_buf);
    gemm_bt_kernel<<<dim3(T_TOK / BM, (HIDDEN + BN - 1) / BN), 128, 0, stream>>>(
        attn_buf, out_w, out_b, out, T_TOK, HIDDEN, ATTN_DIM);
}

// Round 3
// 569.716 us; speedup vs baseline: 3.1799x; 3.1799x over previous
//
#include <hip/hip_runtime.h>
#include <hip/hip_bf16.h>
#include <math.h>

#define T_TOK 1024
#define HIDDEN 2880
#define HD 64
#define NH 64
#define NKV 8
#define SW 128
#define QKV_DIM 5120   // HD*(NH+2*NKV)
#define ATTN_DIM 4096  // NH*HD
#define OW_NPAD 2944   // 2880 padded to multiple of 128

typedef __attribute__((ext_vector_type(8))) short sv8;     // 8 x bf16 fragment
typedef __attribute__((ext_vector_type(4))) float f32x4;   // MFMA accumulator

__device__ __forceinline__ ushort f2bf(float f) {
    union { float f; unsigned u; } v; v.f = f;
    unsigned r = v.u + 0x7fffu + ((v.u >> 16) & 1u);   // round-to-nearest-even
    return (ushort)(r >> 16);
}
__device__ __forceinline__ float bf2f(ushort h) {
    union { unsigned u; float f; } v; v.u = ((unsigned)h) << 16;
    return v.f;
}
__device__ __forceinline__ void gload16(const ushort* g, ushort* l) {
    __builtin_amdgcn_global_load_lds(
        (const __attribute__((address_space(1))) unsigned int*)g,
        (__attribute__((address_space(3))) unsigned int*)l, 16, 0, 0);
}

// ---------------- RoPE table (1024 x 32) ----------------
__global__ void rope_table_kernel(float* __restrict__ cosT, float* __restrict__ sinT) {
    int gid = blockIdx.x * 256 + threadIdx.x;   // < 1024*32
    int i = gid & 31;
    int t = gid >> 5;
    const double d_half = 32.0;
    double freq = pow(150000.0, (double)i / 32.0);
    double lowd  = d_half * log(4096.0 / (32.0 * 2.0 * M_PI)) / log(150000.0);
    double highd = d_half * log(4096.0 / (2.0 * M_PI)) / log(150000.0);
    double ramp = ((double)i - lowd) / (highd - lowd);
    ramp = fmin(fmax(ramp, 0.0), 1.0);
    double m = 1.0 - ramp;
    double inv_freq = (1.0 / (32.0 * freq)) * (1.0 - m) + (1.0 / freq) * m;
    float phase = (float)t * (float)inv_freq;    // fp32 multiply like numpy
    double conc = 0.1 * log(32.0) + 1.0;
    cosT[gid] = (float)(cos((double)phase) * conc);
    sinT[gid] = (float)(sin((double)phase) * conc);
}

// ---------------- split fp32 -> bf16 hi/lo (generic, zero-pads dst) ----------------
__global__ __launch_bounds__(256) void split_kernel(const float* __restrict__ X,
                                                    ushort* __restrict__ hi,
                                                    ushort* __restrict__ lo,
                                                    long n_src, long n_dst) {
    long i = ((long)blockIdx.x * 256 + threadIdx.x) * 4;
    if (i >= n_dst) return;
    float4 v = make_float4(0.f, 0.f, 0.f, 0.f);
    if (i < n_src) v = *(const float4*)(X + i);
    ushort4 h, l;
    h.x = f2bf(v.x); l.x = f2bf(v.x - bf2f(h.x));
    h.y = f2bf(v.y); l.y = f2bf(v.y - bf2f(h.y));
    h.z = f2bf(v.z); l.z = f2bf(v.z - bf2f(h.z));
    h.w = f2bf(v.w); l.w = f2bf(v.w - bf2f(h.w));
    *(ushort4*)(hi + i) = h;
    *(ushort4*)(lo + i) = l;
}

// ---------------- RMSNorm -> split bf16 hi/lo ----------------
__global__ __launch_bounds__(256) void rmsnorm_kernel(const float* __restrict__ x,
                                                      const float* __restrict__ scale,
                                                      ushort* __restrict__ t_hi,
                                                      ushort* __restrict__ t_lo) {
    const int row = blockIdx.x;
    const int tid = threadIdx.x;
    const float4* xr = (const float4*)(x + (size_t)row * HIDDEN);
    float4 v[3];
    float ss = 0.f;
    int cnt = 0;
    for (int i = tid; i < HIDDEN / 4; i += 256) {
        float4 a = xr[i];
        v[cnt++] = a;
        ss += a.x * a.x + a.y * a.y + a.z * a.z + a.w * a.w;
    }
    #pragma unroll
    for (int off = 32; off; off >>= 1) ss += __shfl_xor(ss, off);
    __shared__ float red[4];
    if ((tid & 63) == 0) red[tid >> 6] = ss;
    __syncthreads();
    float total = red[0] + red[1] + red[2] + red[3];
    float inv = rsqrtf(total / (float)HIDDEN + 1e-5f);
    const float4* sc = (const float4*)scale;
    cnt = 0;
    for (int i = tid; i < HIDDEN / 4; i += 256) {
        float4 a = v[cnt++];
        float4 s4 = sc[i];
        float4 o;
        o.x = a.x * inv * s4.x; o.y = a.y * inv * s4.y;
        o.z = a.z * inv * s4.z; o.w = a.w * inv * s4.w;
        ushort4 h, l;
        h.x = f2bf(o.x); l.x = f2bf(o.x - bf2f(h.x));
        h.y = f2bf(o.y); l.y = f2bf(o.y - bf2f(h.y));
        h.z = f2bf(o.z); l.z = f2bf(o.z - bf2f(h.z));
        h.w = f2bf(o.w); l.w = f2bf(o.w - bf2f(h.w));
        *(ushort4*)(t_hi + (size_t)row * HIDDEN + i * 4) = h;
        *(ushort4*)(t_lo + (size_t)row * HIDDEN + i * 4) = l;
    }
}

// ---------------- split-bf16 MFMA GEMM: C[M][N] = A·B^T + bias ----------------
// A: [M][K] as hi/lo bf16, B: [Npad][K] as hi/lo bf16 (Npad = gridDim.y*128, zero-padded)
// tile 128x128, BK=64, 4 waves, 16x16x32 MFMA, global_load_lds staging with
// pre-swizzled source (chunk-col ^= row&7) + swizzled ds_read (conflict-free).
__global__ __launch_bounds__(256) void gemm_mfma_split(
    const ushort* __restrict__ Ahi, const ushort* __restrict__ Alo,
    const ushort* __restrict__ Bhi, const ushort* __restrict__ Blo,
    const float* __restrict__ bias, float* __restrict__ C,
    const int N, const int K)
{
    __shared__ __align__(16) ushort sAhi[128 * 64];
    __shared__ __align__(16) ushort sAlo[128 * 64];
    __shared__ __align__(16) ushort sBhi[128 * 64];
    __shared__ __align__(16) ushort sBlo[128 * 64];

    const int tid = threadIdx.x;
    const int m0 = blockIdx.x * 128;
    const int n0 = blockIdx.y * 128;
    const int w = tid >> 6, lane = tid & 63;
    const int wr = (w >> 1) * 64, wc = (w & 1) * 64;
    const int fr = lane & 15, fq = lane >> 4;

    // staging geometry: tile = 128 rows x 64 bf16 = 1024 chunks of 16B; 4 chunks/thread.
    // LDS dest is linear (chunk c at byte c*16); source column is inverse-swizzled.
    int offA[4], offB[4], loff[4];
    #pragma unroll
    for (int q = 0; q < 4; ++q) {
        int c = tid + q * 256;
        int row = c >> 3, pc = c & 7;
        int gcol = (pc ^ (row & 7)) * 8;          // bf16 units
        offA[q] = (m0 + row) * K + gcol;
        offB[q] = (n0 + row) * K + gcol;
        loff[q] = c * 8;                           // bf16 units
    }

    f32x4 acc[4][4] = {};

    for (int k0 = 0; k0 < K; k0 += 64) {
        #pragma unroll
        for (int q = 0; q < 4; ++q) {
            gload16(Ahi + offA[q] + k0, sAhi + loff[q]);
            gload16(Alo + offA[q] + k0, sAlo + loff[q]);
            gload16(Bhi + offB[q] + k0, sBhi + loff[q]);
            gload16(Blo + offB[q] + k0, sBlo + loff[q]);
        }
        __syncthreads();   // drains vmcnt before barrier (compiler-emitted)
        #pragma unroll
        for (int ks = 0; ks < 2; ++ks) {
            sv8 ahi[4], alo[4], bhi[4], blo[4];
            const int cx = ((ks * 4 + fq) ^ (fr & 7)) * 8;   // swizzled chunk col, bf16 units
            #pragma unroll
            for (int i = 0; i < 4; ++i) {
                int ra = (wr + i * 16 + fr) * 64 + cx;
                ahi[i] = *(const sv8*)(sAhi + ra);
                alo[i] = *(const sv8*)(sAlo + ra);
                int rb = (wc + i * 16 + fr) * 64 + cx;
                bhi[i] = *(const sv8*)(sBhi + rb);
                blo[i] = *(const sv8*)(sBlo + rb);
            }
            #pragma unroll
            for (int i = 0; i < 4; ++i)
                #pragma unroll
                for (int j = 0; j < 4; ++j) {
                    acc[i][j] = __builtin_amdgcn_mfma_f32_16x16x32_bf16(ahi[i], bhi[j], acc[i][j], 0, 0, 0);
                    acc[i][j] = __builtin_amdgcn_mfma_f32_16x16x32_bf16(ahi[i], blo[j], acc[i][j], 0, 0, 0);
                    acc[i][j] = __builtin_amdgcn_mfma_f32_16x16x32_bf16(alo[i], bhi[j], acc[i][j], 0, 0, 0);
                }
        }
        __syncthreads();
    }

    // C/D layout (verified m89/m91): col = lane&15, row = (lane>>4)*4 + reg
    #pragma unroll
    for (int j = 0; j < 4; ++j) {
        int col = n0 + wc + j * 16 + fr;
        if (col < N) {
            float bv = bias[col];
            #pragma unroll
            for (int i = 0; i < 4; ++i) {
                int row = m0 + wr + i * 16 + fq * 4;
                #pragma unroll
                for (int r = 0; r < 4; ++r)
                    C[(size_t)(row + r) * N + col] = acc[i][j][r] + bv;
            }
        }
    }
}

// ---------------- RoPE apply (in-place on qkv fp32) ----------------
__global__ __launch_bounds__(256) void rope_apply_kernel(float* __restrict__ qkv,
                                                         const float* __restrict__ cosT,
                                                         const float* __restrict__ sinT) {
    int gid = blockIdx.x * 256 + threadIdx.x;   // < 1024*72*32
    int i = gid & 31;
    int head = (gid >> 5) % 72;
    int t = gid / (72 * 32);
    size_t base = (size_t)t * QKV_DIM + (head < 64 ? head * 64 : ATTN_DIM + (head - 64) * 64);
    float x1 = qkv[base + i], x2 = qkv[base + 32 + i];
    float c = cosT[t * 32 + i], s = sinT[t * 32 + i];
    qkv[base + i]      = x1 * c - x2 * s;
    qkv[base + 32 + i] = x2 * c + x1 * s;
}

// ---------------- Sliding-window attention with sink -> split bf16 out ----------------
__global__ __launch_bounds__(256) void attn_kernel(const float* __restrict__ qkv,
                                                   const float* __restrict__ sinks,
                                                   ushort* __restrict__ attn_hi,
                                                   ushort* __restrict__ attn_lo) {
    __shared__ __align__(16) float K_lds[128][65];
    __shared__ __align__(16) float V_lds[128][64];
    __shared__ __align__(16) float q_s[8][64];
    __shared__ float w_lds[4][128];
    const int q = blockIdx.x, g = blockIdx.y;
    const int tid = threadIdx.x;
    const int lane = tid & 63, w = tid >> 6;
    const int s = (q - (SW - 1)) > 0 ? (q - (SW - 1)) : 0;
    const int C = q - s + 1;   // 1..128 valid keys

    for (int idx = tid; idx < 8 * 64; idx += 256) {
        int hh = idx >> 6, d = idx & 63;
        q_s[hh][d] = qkv[(size_t)q * QKV_DIM + (g * 8 + hh) * 64 + d];
    }
    for (int idx = tid; idx < C * 16; idx += 256) {
        int r = idx >> 4, c4 = idx & 15;
        const float* krow = qkv + (size_t)(s + r) * QKV_DIM + ATTN_DIM + g * 64 + c4 * 4;
        float4 kv = *(const float4*)krow;
        K_lds[r][c4 * 4 + 0] = kv.x; K_lds[r][c4 * 4 + 1] = kv.y;
        K_lds[r][c4 * 4 + 2] = kv.z; K_lds[r][c4 * 4 + 3] = kv.w;
        float4 vv = *(const float4*)(krow + NKV * 64);
        *(float4*)&V_lds[r][c4 * 4] = vv;
    }
    __syncthreads();

    const float sm_scale = 0.125f;
    for (int hh2 = 0; hh2 < 2; ++hh2) {
        const int hh = w * 2 + hh2;
        const int h = g * 8 + hh;
        float acc0 = 0.f, acc1 = 0.f;
        #pragma unroll 8
        for (int d = 0; d < 64; ++d) {
            float qd = q_s[hh][d];
            acc0 += qd * K_lds[lane][d];
            acc1 += qd * K_lds[lane + 64][d];
        }
        float l0 = (lane < C) ? acc0 * sm_scale : -INFINITY;
        float l1 = (lane + 64 < C) ? acc1 * sm_scale : -INFINITY;
        float sink = sinks[h];
        float mx = fmaxf(fmaxf(l0, l1), sink);
        #pragma unroll
        for (int off = 32; off; off >>= 1) mx = fmaxf(mx, __shfl_xor(mx, off));
        float e0 = expf(l0 - mx), e1 = expf(l1 - mx);
        float sum = e0 + e1;
        #pragma unroll
        for (int off = 32; off; off >>= 1) sum += __shfl_xor(sum, off);
        float inv = 1.f / (sum + expf(sink - mx));
        w_lds[w][lane] = e0 * inv;
        w_lds[w][lane + 64] = e1 * inv;
        __syncthreads();
        float out = 0.f;
        for (int r = 0; r < C; ++r) out += w_lds[w][r] * V_lds[r][lane];
        size_t oidx = (size_t)q * ATTN_DIM + h * 64 + lane;
        ushort h16 = f2bf(out);
        attn_hi[oidx] = h16;
        attn_lo[oidx] = f2bf(out - bf2f(h16));
        __syncthreads();
    }
}

extern "C" void kernel_launch(void* const* d_in, const int* in_sizes, int n_in,
                              void* d_out, int out_size, void* d_ws, size_t ws_size,
                              hipStream_t stream) {
    const float* x          = (const float*)d_in[0];
    const float* norm_scale = (const float*)d_in[1];
    const float* qkv_w      = (const float*)d_in[2];
    const float* qkv_b      = (const float*)d_in[3];
    const float* out_w      = (const float*)d_in[4];
    const float* out_b      = (const float*)d_in[5];
    const float* sinks      = (const float*)d_in[6];
    float* out = (float*)d_out;

    char* p = (char*)d_ws;
    auto alloc = [&](size_t bytes) { char* r = p; p += (bytes + 255) & ~(size_t)255; return r; };
    // Weight split buffers: qkv_w split is dead after GEMM1, so out_w's split
    // (done after GEMM1) aliases the same space. Size = max of the two needs.
    const size_t W_ELEMS = (size_t)QKV_DIM * HIDDEN;   // 14.7M > OW_NPAD*ATTN_DIM? no: 12.06M. max is qkv.
    const size_t W_ELEMS2 = (size_t)OW_NPAD * ATTN_DIM;
    const size_t W_MAX = W_ELEMS > W_ELEMS2 ? W_ELEMS : W_ELEMS2;
    ushort* w_hi  = (ushort*)alloc(W_MAX * 2);
    ushort* w_lo  = (ushort*)alloc(W_MAX * 2);
    // activations: rmsnorm out (1024x2880) and attn out (1024x4096) alias too.
    ushort* ab_hi  = (ushort*)alloc((size_t)T_TOK * ATTN_DIM * 2);
    ushort* ab_lo  = (ushort*)alloc((size_t)T_TOK * ATTN_DIM * 2);
    float*  qkv_buf = (float*)alloc((size_t)T_TOK * QKV_DIM * 4);
    float*  cosT   = (float*)alloc((size_t)T_TOK * 32 * 4);
    float*  sinT   = (float*)alloc((size_t)T_TOK * 32 * 4);

    rope_table_kernel<<<(T_TOK * 32) / 256, 256, 0, stream>>>(cosT, sinT);

    long n_qw = (long)QKV_DIM * HIDDEN;
    split_kernel<<<(int)(n_qw / 4 / 256), 256, 0, stream>>>(qkv_w, w_hi, w_lo, n_qw, n_qw);

    rmsnorm_kernel<<<T_TOK, 256, 0, stream>>>(x, norm_scale, ab_hi, ab_lo);

    gemm_mfma_split<<<dim3(T_TOK / 128, QKV_DIM / 128), 256, 0, stream>>>(
        ab_hi, ab_lo, w_hi, w_lo, qkv_b, qkv_buf, QKV_DIM, HIDDEN);

    rope_apply_kernel<<<(T_TOK * 72 * 32) / 256, 256, 0, stream>>>(qkv_buf, cosT, sinT);

    attn_kernel<<<dim3(T_TOK, NKV), 256, 0, stream>>>(qkv_buf, sinks, ab_hi, ab_lo);

    // out_w split into the (now dead) qkv_w split buffers
    long n_ow_src = (long)HIDDEN * ATTN_DIM;
    long n_ow_dst = (long)OW_NPAD * ATTN_DIM;
    split_kernel<<<(int)(n_ow_dst / 4 / 256), 256, 0, stream>>>(out_w, w_hi, w_lo, n_ow_src, n_ow_dst);

    gemm_mfma_split<<<dim3(T_TOK / 128, OW_NPAD / 128), 256, 0, stream>>>(
        ab_hi, ab_lo, w_hi, w_lo, out_b, out, HIDDEN, ATTN_DIM);
}

// Round 5
// 439.996 us; speedup vs baseline: 4.1174x; 1.2948x over previous
//
#include <hip/hip_runtime.h>
#include <hip/hip_bf16.h>
#include <math.h>

#define T_TOK 1024
#define HIDDEN 2880
#define HD 64
#define NH 64
#define NKV 8
#define SW 128
#define QKV_DIM 5120   // HD*(NH+2*NKV)
#define ATTN_DIM 4096  // NH*HD
#define OW_NPAD 2944   // 2880 padded to multiple of 128

typedef __attribute__((ext_vector_type(8))) short sv8;       // 8 x bf16 fragment
typedef __attribute__((ext_vector_type(8))) _Float16 h8;     // 8 x f16 fragment
typedef __attribute__((ext_vector_type(4))) float f32x4;     // MFMA accumulator

__device__ __forceinline__ ushort f2bf(float f) {
    union { float f; unsigned u; } v; v.f = f;
    unsigned r = v.u + 0x7fffu + ((v.u >> 16) & 1u);   // round-to-nearest-even
    return (ushort)(r >> 16);
}
__device__ __forceinline__ float bf2f(ushort h) {
    union { unsigned u; float f; } v; v.u = ((unsigned)h) << 16;
    return v.f;
}
__device__ __forceinline__ void gload16(const ushort* g, ushort* l) {
    __builtin_amdgcn_global_load_lds(
        (const __attribute__((address_space(1))) unsigned int*)g,
        (__attribute__((address_space(3))) unsigned int*)l, 16, 0, 0);
}

// ---------------- RoPE table (1024 x 32) ----------------
__global__ void rope_table_kernel(float* __restrict__ cosT, float* __restrict__ sinT) {
    int gid = blockIdx.x * 256 + threadIdx.x;   // < 1024*32
    int i = gid & 31;
    int t = gid >> 5;
    const double d_half = 32.0;
    double freq = pow(150000.0, (double)i / 32.0);
    double lowd  = d_half * log(4096.0 / (32.0 * 2.0 * M_PI)) / log(150000.0);
    double highd = d_half * log(4096.0 / (2.0 * M_PI)) / log(150000.0);
    double ramp = ((double)i - lowd) / (highd - lowd);
    ramp = fmin(fmax(ramp, 0.0), 1.0);
    double m = 1.0 - ramp;
    double inv_freq = (1.0 / (32.0 * freq)) * (1.0 - m) + (1.0 / freq) * m;
    float phase = (float)t * (float)inv_freq;    // fp32 multiply like numpy
    double conc = 0.1 * log(32.0) + 1.0;
    cosT[gid] = (float)(cos((double)phase) * conc);
    sinT[gid] = (float)(sin((double)phase) * conc);
}

// ---------------- split fp32 -> bf16 hi/lo (generic, zero-pads dst) ----------------
__global__ __launch_bounds__(256) void split_kernel(const float* __restrict__ X,
                                                    ushort* __restrict__ hi,
                                                    ushort* __restrict__ lo,
                                                    long n_src, long n_dst) {
    long i = ((long)blockIdx.x * 256 + threadIdx.x) * 4;
    if (i >= n_dst) return;
    float4 v = make_float4(0.f, 0.f, 0.f, 0.f);
    if (i < n_src) v = *(const float4*)(X + i);
    ushort4 h, l;
    h.x = f2bf(v.x); l.x = f2bf(v.x - bf2f(h.x));
    h.y = f2bf(v.y); l.y = f2bf(v.y - bf2f(h.y));
    h.z = f2bf(v.z); l.z = f2bf(v.z - bf2f(h.z));
    h.w = f2bf(v.w); l.w = f2bf(v.w - bf2f(h.w));
    *(ushort4*)(hi + i) = h;
    *(ushort4*)(lo + i) = l;
}

// ---------------- RMSNorm -> split bf16 hi/lo ----------------
__global__ __launch_bounds__(256) void rmsnorm_kernel(const float* __restrict__ x,
                                                      const float* __restrict__ scale,
                                                      ushort* __restrict__ t_hi,
                                                      ushort* __restrict__ t_lo) {
    const int row = blockIdx.x;
    const int tid = threadIdx.x;
    const float4* xr = (const float4*)(x + (size_t)row * HIDDEN);
    float4 v[3];
    float ss = 0.f;
    int cnt = 0;
    for (int i = tid; i < HIDDEN / 4; i += 256) {
        float4 a = xr[i];
        v[cnt++] = a;
        ss += a.x * a.x + a.y * a.y + a.z * a.z + a.w * a.w;
    }
    #pragma unroll
    for (int off = 32; off; off >>= 1) ss += __shfl_xor(ss, off);
    __shared__ float red[4];
    if ((tid & 63) == 0) red[tid >> 6] = ss;
    __syncthreads();
    float total = red[0] + red[1] + red[2] + red[3];
    float inv = rsqrtf(total / (float)HIDDEN + 1e-5f);
    const float4* sc = (const float4*)scale;
    cnt = 0;
    for (int i = tid; i < HIDDEN / 4; i += 256) {
        float4 a = v[cnt++];
        float4 s4 = sc[i];
        float4 o;
        o.x = a.x * inv * s4.x; o.y = a.y * inv * s4.y;
        o.z = a.z * inv * s4.z; o.w = a.w * inv * s4.w;
        ushort4 h, l;
        h.x = f2bf(o.x); l.x = f2bf(o.x - bf2f(h.x));
        h.y = f2bf(o.y); l.y = f2bf(o.y - bf2f(h.y));
        h.z = f2bf(o.z); l.z = f2bf(o.z - bf2f(h.z));
        h.w = f2bf(o.w); l.w = f2bf(o.w - bf2f(h.w));
        *(ushort4*)(t_hi + (size_t)row * HIDDEN + i * 4) = h;
        *(ushort4*)(t_lo + (size_t)row * HIDDEN + i * 4) = l;
    }
}

// ---------------- split-bf16 MFMA GEMM: C[M][N] = A·B^T + bias ----------------
__global__ __launch_bounds__(256) void gemm_mfma_split(
    const ushort* __restrict__ Ahi, const ushort* __restrict__ Alo,
    const ushort* __restrict__ Bhi, const ushort* __restrict__ Blo,
    const float* __restrict__ bias, float* __restrict__ C,
    const int N, const int K)
{
    __shared__ __align__(16) ushort sAhi[128 * 64];
    __shared__ __align__(16) ushort sAlo[128 * 64];
    __shared__ __align__(16) ushort sBhi[128 * 64];
    __shared__ __align__(16) ushort sBlo[128 * 64];

    const int tid = threadIdx.x;
    const int m0 = blockIdx.x * 128;
    const int n0 = blockIdx.y * 128;
    const int w = tid >> 6, lane = tid & 63;
    const int wr = (w >> 1) * 64, wc = (w & 1) * 64;
    const int fr = lane & 15, fq = lane >> 4;

    int offA[4], offB[4], loff[4];
    #pragma unroll
    for (int q = 0; q < 4; ++q) {
        int c = tid + q * 256;
        int row = c >> 3, pc = c & 7;
        int gcol = (pc ^ (row & 7)) * 8;          // bf16 units
        offA[q] = (m0 + row) * K + gcol;
        offB[q] = (n0 + row) * K + gcol;
        loff[q] = c * 8;                           // bf16 units
    }

    f32x4 acc[4][4] = {};

    for (int k0 = 0; k0 < K; k0 += 64) {
        #pragma unroll
        for (int q = 0; q < 4; ++q) {
            gload16(Ahi + offA[q] + k0, sAhi + loff[q]);
            gload16(Alo + offA[q] + k0, sAlo + loff[q]);
            gload16(Bhi + offB[q] + k0, sBhi + loff[q]);
            gload16(Blo + offB[q] + k0, sBlo + loff[q]);
        }
        __syncthreads();
        #pragma unroll
        for (int ks = 0; ks < 2; ++ks) {
            sv8 ahi[4], alo[4], bhi[4], blo[4];
            const int cx = ((ks * 4 + fq) ^ (fr & 7)) * 8;
            #pragma unroll
            for (int i = 0; i < 4; ++i) {
                int ra = (wr + i * 16 + fr) * 64 + cx;
                ahi[i] = *(const sv8*)(sAhi + ra);
                alo[i] = *(const sv8*)(sAlo + ra);
                int rb = (wc + i * 16 + fr) * 64 + cx;
                bhi[i] = *(const sv8*)(sBhi + rb);
                blo[i] = *(const sv8*)(sBlo + rb);
            }
            #pragma unroll
            for (int i = 0; i < 4; ++i)
                #pragma unroll
                for (int j = 0; j < 4; ++j) {
                    acc[i][j] = __builtin_amdgcn_mfma_f32_16x16x32_bf16(ahi[i], bhi[j], acc[i][j], 0, 0, 0);
                    acc[i][j] = __builtin_amdgcn_mfma_f32_16x16x32_bf16(ahi[i], blo[j], acc[i][j], 0, 0, 0);
                    acc[i][j] = __builtin_amdgcn_mfma_f32_16x16x32_bf16(alo[i], bhi[j], acc[i][j], 0, 0, 0);
                }
        }
        __syncthreads();
    }

    #pragma unroll
    for (int j = 0; j < 4; ++j) {
        int col = n0 + wc + j * 16 + fr;
        if (col < N) {
            float bv = bias[col];
            #pragma unroll
            for (int i = 0; i < 4; ++i) {
                int row = m0 + wr + i * 16 + fq * 4;
                #pragma unroll
                for (int r = 0; r < 4; ++r)
                    C[(size_t)(row + r) * N + col] = acc[i][j][r] + bv;
            }
        }
    }
}

// ---------------- RoPE apply (in-place on qkv fp32) ----------------
__global__ __launch_bounds__(256) void rope_apply_kernel(float* __restrict__ qkv,
                                                         const float* __restrict__ cosT,
                                                         const float* __restrict__ sinT) {
    int gid = blockIdx.x * 256 + threadIdx.x;   // < 1024*72*32
    int i = gid & 31;
    int head = (gid >> 5) % 72;
    int t = gid / (72 * 32);
    size_t base = (size_t)t * QKV_DIM + (head < 64 ? head * 64 : ATTN_DIM + (head - 64) * 64);
    float x1 = qkv[base + i], x2 = qkv[base + 32 + i];
    float c = cosT[t * 32 + i], s = sinT[t * 32 + i];
    qkv[base + i]      = x1 * c - x2 * s;
    qkv[base + 32 + i] = x2 * c + x1 * s;
}

// ---------------- MFMA sliding-window attention with sink ----------------
// block = (q-tile of 32, group g). rows = 8 heads x 32 q = 256; wave w owns rows
// [64w,64w+64) = heads {2w,2w+1}. Key slab: 160 keys from s0 = max(0,q0-127)
// covers every valid window (j in [qr, qr+127]). Single-tile softmax (no online).
// QK^T: bf16 hi/lo 3-term MFMA. PV: f16 W (unnormalized e) x f16 V, normalize in
// epilogue. W LDS buffer aliases dead K region. All LDS XOR-swizzled (^row&7).
__global__ __launch_bounds__(256, 1) void attn_mfma_kernel(
    const float* __restrict__ qkv, const float* __restrict__ sinks,
    ushort* __restrict__ attn_hi, ushort* __restrict__ attn_lo)
{
    __shared__ __align__(16) char smem[122880];
    ushort*   Khi = (ushort*)smem;                    // [160][64] bf16 (20480 B)
    ushort*   Klo = (ushort*)(smem + 20480);          // [160][64] bf16
    _Float16* Wl  = (_Float16*)smem;                  // [256][192] f16 (98304 B) aliases K
    _Float16* Vt  = (_Float16*)(smem + 98304);        // [64][192] f16 (24576 B)

    const int q0 = blockIdx.x * 32;
    const int g  = blockIdx.y;
    const int tid = threadIdx.x;
    const int w = tid >> 6, lane = tid & 63;
    const int fr = lane & 15, fq = lane >> 4;
    const int s0 = (q0 > 127) ? (q0 - 127) : 0;
    const int kmax = q0 + 32 - s0;                    // 32..159 staged keys

    // ---- stage K (bf16 hi/lo, chunk^=(row&7) swizzle) and V^T (f16, swizzled) ----
    for (int idx = tid; idx < 160 * 8; idx += 256) {
        int j = idx >> 3, c = idx & 7;
        float kv[8], vv[8];
        if (j < kmax) {
            const float* src = qkv + (size_t)(s0 + j) * QKV_DIM + ATTN_DIM + g * 64 + c * 8;
            *(float4*)&kv[0] = *(const float4*)src;
            *(float4*)&kv[4] = *(const float4*)(src + 4);
            const float* srcv = src + NKV * 64;
            *(float4*)&vv[0] = *(const float4*)srcv;
            *(float4*)&vv[4] = *(const float4*)(srcv + 4);
        } else {
            #pragma unroll
            for (int e = 0; e < 8; ++e) { kv[e] = 0.f; vv[e] = 0.f; }
        }
        sv8 hv, lv;
        #pragma unroll
        for (int e = 0; e < 8; ++e) {
            ushort h = f2bf(kv[e]);
            hv[e] = (short)h;
            lv[e] = (short)f2bf(kv[e] - bf2f(h));
        }
        int cs = c ^ (j & 7);
        *(sv8*)(Khi + j * 64 + cs * 8) = hv;
        *(sv8*)(Klo + j * 64 + cs * 8) = lv;
        // V transposed: Vt[d][key j], key-chunk cj = j>>3 swizzled with (d&7)
        int cj = j >> 3, jl = j & 7;
        #pragma unroll
        for (int e = 0; e < 8; ++e) {
            int d = c * 8 + e;
            int cp = (cj & 24) | ((cj & 7) ^ (d & 7));
            Vt[d * 192 + cp * 8 + jl] = (_Float16)vv[e];
        }
    }

    // ---- Q fragments in registers (A-layout: row=fr, k-chunk=fq) ----
    sv8 qhi[4][2], qlo[4][2];
    #pragma unroll
    for (int rf = 0; rf < 4; ++rf) {
        int hl = w * 2 + (rf >> 1);
        int qr = (rf & 1) * 16 + fr;
        const float* qrow = qkv + (size_t)(q0 + qr) * QKV_DIM + (g * 8 + hl) * 64;
        #pragma unroll
        for (int ks = 0; ks < 2; ++ks) {
            float v[8];
            *(float4*)&v[0] = *(const float4*)(qrow + ks * 32 + fq * 8);
            *(float4*)&v[4] = *(const float4*)(qrow + ks * 32 + fq * 8 + 4);
            #pragma unroll
            for (int e = 0; e < 8; ++e) {
                ushort h = f2bf(v[e]);
                qhi[rf][ks][e] = (short)h;
                qlo[rf][ks][e] = (short)f2bf(v[e] - bf2f(h));
            }
        }
    }

    __syncthreads();

    // ---- QK^T: S[rows 64/wave][keys 160], 3-term split ----
    const int ncf = (kmax + 15) >> 4;
    f32x4 S[4][10] = {};
    #pragma unroll
    for (int ks = 0; ks < 2; ++ks) {
        #pragma unroll
        for (int cf = 0; cf < 10; ++cf) {
            if (cf < ncf) {
                int key = cf * 16 + fr;
                int cs = (ks * 4 + fq) ^ (key & 7);
                sv8 kh = *(const sv8*)(Khi + key * 64 + cs * 8);
                sv8 kl = *(const sv8*)(Klo + key * 64 + cs * 8);
                #pragma unroll
                for (int rf = 0; rf < 4; ++rf) {
                    S[rf][cf] = __builtin_amdgcn_mfma_f32_16x16x32_bf16(qhi[rf][ks], kh, S[rf][cf], 0, 0, 0);
                    S[rf][cf] = __builtin_amdgcn_mfma_f32_16x16x32_bf16(qlo[rf][ks], kh, S[rf][cf], 0, 0, 0);
                    S[rf][cf] = __builtin_amdgcn_mfma_f32_16x16x32_bf16(qhi[rf][ks], kl, S[rf][cf], 0, 0, 0);
                }
            }
        }
    }

    __syncthreads();   // all waves done reading K; W may now overwrite it

    // ---- softmax (per row, 16-lane shfl reduce) + unnormalized e -> W (f16) ----
    float inv_s[4][4];
    #pragma unroll
    for (int rf = 0; rf < 4; ++rf) {
        float sink = sinks[g * 8 + w * 2 + (rf >> 1)];
        #pragma unroll
        for (int r = 0; r < 4; ++r) {
            int q = q0 + (rf & 1) * 16 + fq * 4 + r;
            float sv[10];
            float mx = sink;
            #pragma unroll
            for (int cf = 0; cf < 10; ++cf) {
                float v = S[rf][cf][r] * 0.125f;
                int kg = s0 + cf * 16 + fr;
                bool ok = (cf < ncf) && (kg <= q) && (kg + SW > q);
                v = ok ? v : -INFINITY;
                sv[cf] = v;
                mx = fmaxf(mx, v);
            }
            #pragma unroll
            for (int off = 1; off < 16; off <<= 1) mx = fmaxf(mx, __shfl_xor(mx, off));
            float sum = 0.f;
            #pragma unroll
            for (int cf = 0; cf < 10; ++cf) {
                float e = __expf(sv[cf] - mx);
                sv[cf] = e;
                sum += e;
            }
            #pragma unroll
            for (int off = 1; off < 16; off <<= 1) sum += __shfl_xor(sum, off);
            sum += __expf(sink - mx);
            inv_s[rf][r] = 1.f / sum;
            int row = w * 64 + rf * 16 + fq * 4 + r;
            #pragma unroll
            for (int cf = 0; cf < 10; ++cf) {
                if (cf < ncf) {
                    int key = cf * 16 + fr;
                    int cj = key >> 3;
                    int cp = (cj & 24) | ((cj & 7) ^ (row & 7));
                    Wl[row * 192 + cp * 8 + (key & 7)] = (_Float16)sv[cf];
                }
            }
        }
    }

    __syncthreads();

    // ---- PV: out[64 rows][64 d] = W · V (f16 MFMA), normalize in epilogue ----
    const int nks = (kmax + 31) >> 5;
    f32x4 O[4][4] = {};
    #pragma unroll
    for (int ks = 0; ks < 5; ++ks) {
        if (ks < nks) {
            h8 a[4], b[4];
            int cj = ks * 4 + fq;
            #pragma unroll
            for (int rf = 0; rf < 4; ++rf) {
                int row = w * 64 + rf * 16 + fr;
                int cp = (cj & 24) | ((cj & 7) ^ (row & 7));
                a[rf] = *(const h8*)(Wl + row * 192 + cp * 8);
            }
            #pragma unroll
            for (int df = 0; df < 4; ++df) {
                int d = df * 16 + fr;
                int cp = (cj & 24) | ((cj & 7) ^ (d & 7));
                b[df] = *(const h8*)(Vt + d * 192 + cp * 8);
            }
            #pragma unroll
            for (int rf = 0; rf < 4; ++rf)
                #pragma unroll
                for (int df = 0; df < 4; ++df)
                    O[rf][df] = __builtin_amdgcn_mfma_f32_16x16x32_f16(a[rf], b[df], O[rf][df], 0, 0, 0);
        }
    }

    // ---- epilogue: normalize, split hi/lo bf16 ----
    #pragma unroll
    for (int rf = 0; rf < 4; ++rf) {
        int H = g * 8 + w * 2 + (rf >> 1);
        #pragma unroll
        for (int df = 0; df < 4; ++df) {
            int d = df * 16 + fr;
            #pragma unroll
            for (int r = 0; r < 4; ++r) {
                int qr = (rf & 1) * 16 + fq * 4 + r;
                float v = O[rf][df][r] * inv_s[rf][r];
                size_t addr = (size_t)(q0 + qr) * ATTN_DIM + H * 64 + d;
                ushort h16 = f2bf(v);
                attn_hi[addr] = h16;
                attn_lo[addr] = f2bf(v - bf2f(h16));
            }
        }
    }
}

extern "C" void kernel_launch(void* const* d_in, const int* in_sizes, int n_in,
                              void* d_out, int out_size, void* d_ws, size_t ws_size,
                              hipStream_t stream) {
    const float* x          = (const float*)d_in[0];
    const float* norm_scale = (const float*)d_in[1];
    const float* qkv_w      = (const float*)d_in[2];
    const float* qkv_b      = (const float*)d_in[3];
    const float* out_w      = (const float*)d_in[4];
    const float* out_b      = (const float*)d_in[5];
    const float* sinks      = (const float*)d_in[6];
    float* out = (float*)d_out;

    char* p = (char*)d_ws;
    auto alloc = [&](size_t bytes) { char* r = p; p += (bytes + 255) & ~(size_t)255; return r; };
    const size_t W_ELEMS  = (size_t)QKV_DIM * HIDDEN;
    const size_t W_ELEMS2 = (size_t)OW_NPAD * ATTN_DIM;
    const size_t W_MAX = W_ELEMS > W_ELEMS2 ? W_ELEMS : W_ELEMS2;
    ushort* w_hi  = (ushort*)alloc(W_MAX * 2);
    ushort* w_lo  = (ushort*)alloc(W_MAX * 2);
    ushort* ab_hi  = (ushort*)alloc((size_t)T_TOK * ATTN_DIM * 2);
    ushort* ab_lo  = (ushort*)alloc((size_t)T_TOK * ATTN_DIM * 2);
    float*  qkv_buf = (float*)alloc((size_t)T_TOK * QKV_DIM * 4);
    float*  cosT   = (float*)alloc((size_t)T_TOK * 32 * 4);
    float*  sinT   = (float*)alloc((size_t)T_TOK * 32 * 4);

    rope_table_kernel<<<(T_TOK * 32) / 256, 256, 0, stream>>>(cosT, sinT);

    long n_qw = (long)QKV_DIM * HIDDEN;
    split_kernel<<<(int)(n_qw / 4 / 256), 256, 0, stream>>>(qkv_w, w_hi, w_lo, n_qw, n_qw);

    rmsnorm_kernel<<<T_TOK, 256, 0, stream>>>(x, norm_scale, ab_hi, ab_lo);

    gemm_mfma_split<<<dim3(T_TOK / 128, QKV_DIM / 128), 256, 0, stream>>>(
        ab_hi, ab_lo, w_hi, w_lo, qkv_b, qkv_buf, QKV_DIM, HIDDEN);

    rope_apply_kernel<<<(T_TOK * 72 * 32) / 256, 256, 0, stream>>>(qkv_buf, cosT, sinT);

    attn_mfma_kernel<<<dim3(T_TOK / 32, NKV), 256, 0, stream>>>(qkv_buf, sinks, ab_hi, ab_lo);

    long n_ow_src = (long)HIDDEN * ATTN_DIM;
    long n_ow_dst = (long)OW_NPAD * ATTN_DIM;
    split_kernel<<<(int)(n_ow_dst / 4 / 256), 256, 0, stream>>>(out_w, w_hi, w_lo, n_ow_src, n_ow_dst);

    gemm_mfma_split<<<dim3(T_TOK / 128, OW_NPAD / 128), 256, 0, stream>>>(
        ab_hi, ab_lo, w_hi, w_lo, out_b, out, HIDDEN, ATTN_DIM);
}

// Round 6
// 399.194 us; speedup vs baseline: 4.5383x; 1.1022x over previous
//
#include <hip/hip_runtime.h>
#include <hip/hip_bf16.h>
#include <math.h>

#define T_TOK 1024
#define HIDDEN 2880
#define HD 64
#define NH 64
#define NKV 8
#define SW 128
#define QKV_DIM 5120   // HD*(NH+2*NKV)
#define ATTN_DIM 4096  // NH*HD
#define OW_NPAD 2944   // 2880 padded to multiple of 128
#define ROPE_END 4608  // cols < this (q+k heads) get RoPE in GEMM1 epilogue

typedef __attribute__((ext_vector_type(8))) short sv8;       // 8 x bf16 fragment
typedef __attribute__((ext_vector_type(8))) _Float16 h8;     // 8 x f16 fragment
typedef __attribute__((ext_vector_type(4))) float f32x4;     // MFMA accumulator

__device__ __forceinline__ ushort f2bf(float f) {
    union { float f; unsigned u; } v; v.f = f;
    unsigned r = v.u + 0x7fffu + ((v.u >> 16) & 1u);   // round-to-nearest-even
    return (ushort)(r >> 16);
}
__device__ __forceinline__ float bf2f(ushort h) {
    union { unsigned u; float f; } v; v.u = ((unsigned)h) << 16;
    return v.f;
}
__device__ __forceinline__ void gload16(const ushort* g, ushort* l) {
    __builtin_amdgcn_global_load_lds(
        (const __attribute__((address_space(1))) unsigned int*)g,
        (__attribute__((address_space(3))) unsigned int*)l, 16, 0, 0);
}

// ---------------- RoPE table (1024 x 32) ----------------
__global__ void rope_table_kernel(float* __restrict__ cosT, float* __restrict__ sinT) {
    int gid = blockIdx.x * 256 + threadIdx.x;   // < 1024*32
    int i = gid & 31;
    int t = gid >> 5;
    const double d_half = 32.0;
    double freq = pow(150000.0, (double)i / 32.0);
    double lowd  = d_half * log(4096.0 / (32.0 * 2.0 * M_PI)) / log(150000.0);
    double highd = d_half * log(4096.0 / (2.0 * M_PI)) / log(150000.0);
    double ramp = ((double)i - lowd) / (highd - lowd);
    ramp = fmin(fmax(ramp, 0.0), 1.0);
    double m = 1.0 - ramp;
    double inv_freq = (1.0 / (32.0 * freq)) * (1.0 - m) + (1.0 / freq) * m;
    float phase = (float)t * (float)inv_freq;    // fp32 multiply like numpy
    double conc = 0.1 * log(32.0) + 1.0;
    cosT[gid] = (float)(cos((double)phase) * conc);
    sinT[gid] = (float)(sin((double)phase) * conc);
}

// ---------------- split fp32 -> bf16 hi/lo (generic, zero-pads dst) ----------------
__global__ __launch_bounds__(256) void split_kernel(const float* __restrict__ X,
                                                    ushort* __restrict__ hi,
                                                    ushort* __restrict__ lo,
                                                    long n_src, long n_dst) {
    long i = ((long)blockIdx.x * 256 + threadIdx.x) * 4;
    if (i >= n_dst) return;
    float4 v = make_float4(0.f, 0.f, 0.f, 0.f);
    if (i < n_src) v = *(const float4*)(X + i);
    ushort4 h, l;
    h.x = f2bf(v.x); l.x = f2bf(v.x - bf2f(h.x));
    h.y = f2bf(v.y); l.y = f2bf(v.y - bf2f(h.y));
    h.z = f2bf(v.z); l.z = f2bf(v.z - bf2f(h.z));
    h.w = f2bf(v.w); l.w = f2bf(v.w - bf2f(h.w));
    *(ushort4*)(hi + i) = h;
    *(ushort4*)(lo + i) = l;
}

// ---------------- RMSNorm -> split bf16 hi/lo ----------------
__global__ __launch_bounds__(256) void rmsnorm_kernel(const float* __restrict__ x,
                                                      const float* __restrict__ scale,
                                                      ushort* __restrict__ t_hi,
                                                      ushort* __restrict__ t_lo) {
    const int row = blockIdx.x;
    const int tid = threadIdx.x;
    const float4* xr = (const float4*)(x + (size_t)row * HIDDEN);
    float4 v[3];
    float ss = 0.f;
    int cnt = 0;
    for (int i = tid; i < HIDDEN / 4; i += 256) {
        float4 a = xr[i];
        v[cnt++] = a;
        ss += a.x * a.x + a.y * a.y + a.z * a.z + a.w * a.w;
    }
    #pragma unroll
    for (int off = 32; off; off >>= 1) ss += __shfl_xor(ss, off);
    __shared__ float red[4];
    if ((tid & 63) == 0) red[tid >> 6] = ss;
    __syncthreads();
    float total = red[0] + red[1] + red[2] + red[3];
    float inv = rsqrtf(total / (float)HIDDEN + 1e-5f);
    const float4* sc = (const float4*)scale;
    cnt = 0;
    for (int i = tid; i < HIDDEN / 4; i += 256) {
        float4 a = v[cnt++];
        float4 s4 = sc[i];
        float4 o;
        o.x = a.x * inv * s4.x; o.y = a.y * inv * s4.y;
        o.z = a.z * inv * s4.z; o.w = a.w * inv * s4.w;
        ushort4 h, l;
        h.x = f2bf(o.x); l.x = f2bf(o.x - bf2f(h.x));
        h.y = f2bf(o.y); l.y = f2bf(o.y - bf2f(h.y));
        h.z = f2bf(o.z); l.z = f2bf(o.z - bf2f(h.z));
        h.w = f2bf(o.w); l.w = f2bf(o.w - bf2f(h.w));
        *(ushort4*)(t_hi + (size_t)row * HIDDEN + i * 4) = h;
        *(ushort4*)(t_lo + (size_t)row * HIDDEN + i * 4) = l;
    }
}

// ---------------- split-bf16 MFMA GEMM: C[M][N] = A·B^T + bias ----------------
// Tile 64x128, BK=64, 4 waves (2x2, wave tile 32x64), LDS 48 KB -> 3 blocks/CU.
// 1D grid with bijective XCD swizzle (m-major inside each XCD chunk so the 16
// m-blocks sharing a B-panel are co-resident on one XCD's L2).
// ROPE: fused RoPE epilogue for cols < ROPE_END (GEMM1 only).
template <bool ROPE>
__global__ __launch_bounds__(256, 2) void gemm_mfma_split(
    const ushort* __restrict__ Ahi, const ushort* __restrict__ Alo,
    const ushort* __restrict__ Bhi, const ushort* __restrict__ Blo,
    const float* __restrict__ bias, float* __restrict__ C,
    const float* __restrict__ cosT, const float* __restrict__ sinT,
    const int N, const int K)
{
    __shared__ __align__(16) ushort sAhi[64 * 64];
    __shared__ __align__(16) ushort sAlo[64 * 64];
    __shared__ __align__(16) ushort sBhi[128 * 64];
    __shared__ __align__(16) ushort sBlo[128 * 64];

    const int tid = threadIdx.x;
    // bijective XCD swizzle: launched L -> logical lin; m fastest within chunk.
    const int cpx = gridDim.x >> 3;              // grid % 8 == 0 by construction
    const int L = blockIdx.x;
    const int lin = (L & 7) * cpx + (L >> 3);
    const int m0 = (lin & 15) * 64;              // M = 1024 = 16 x 64 always
    const int n0 = (lin >> 4) * 128;

    const int w = tid >> 6, lane = tid & 63;
    const int wr = (w >> 1) * 32, wc = (w & 1) * 64;
    const int fr = lane & 15, fq = lane >> 4;

    // staging: A = 512 chunks of 16B (2/thread), B = 1024 chunks (4/thread).
    int offA[2], loffA[2], offB[4], loffB[4];
    #pragma unroll
    for (int q = 0; q < 2; ++q) {
        int c = tid + q * 256;
        int row = c >> 3, pc = c & 7;
        int gcol = (pc ^ (row & 7)) * 8;
        offA[q] = (m0 + row) * K + gcol;
        loffA[q] = c * 8;
    }
    #pragma unroll
    for (int q = 0; q < 4; ++q) {
        int c = tid + q * 256;
        int row = c >> 3, pc = c & 7;
        int gcol = (pc ^ (row & 7)) * 8;
        offB[q] = (n0 + row) * K + gcol;
        loffB[q] = c * 8;
    }

    f32x4 acc[2][4] = {};

    for (int k0 = 0; k0 < K; k0 += 64) {
        #pragma unroll
        for (int q = 0; q < 2; ++q) {
            gload16(Ahi + offA[q] + k0, sAhi + loffA[q]);
            gload16(Alo + offA[q] + k0, sAlo + loffA[q]);
        }
        #pragma unroll
        for (int q = 0; q < 4; ++q) {
            gload16(Bhi + offB[q] + k0, sBhi + loffB[q]);
            gload16(Blo + offB[q] + k0, sBlo + loffB[q]);
        }
        __syncthreads();
        #pragma unroll
        for (int ks = 0; ks < 2; ++ks) {
            sv8 ahi[2], alo[2], bhi[4], blo[4];
            const int cx = ((ks * 4 + fq) ^ (fr & 7)) * 8;
            #pragma unroll
            for (int i = 0; i < 2; ++i) {
                int ra = (wr + i * 16 + fr) * 64 + cx;
                ahi[i] = *(const sv8*)(sAhi + ra);
                alo[i] = *(const sv8*)(sAlo + ra);
            }
            #pragma unroll
            for (int j = 0; j < 4; ++j) {
                int rb = (wc + j * 16 + fr) * 64 + cx;
                bhi[j] = *(const sv8*)(sBhi + rb);
                blo[j] = *(const sv8*)(sBlo + rb);
            }
            #pragma unroll
            for (int i = 0; i < 2; ++i)
                #pragma unroll
                for (int j = 0; j < 4; ++j) {
                    acc[i][j] = __builtin_amdgcn_mfma_f32_16x16x32_bf16(ahi[i], bhi[j], acc[i][j], 0, 0, 0);
                    acc[i][j] = __builtin_amdgcn_mfma_f32_16x16x32_bf16(ahi[i], blo[j], acc[i][j], 0, 0, 0);
                    acc[i][j] = __builtin_amdgcn_mfma_f32_16x16x32_bf16(alo[i], bhi[j], acc[i][j], 0, 0, 0);
                }
        }
        __syncthreads();
    }

    // C/D layout: col = lane&15, row = (lane>>4)*4 + reg
    if (ROPE) {
        // pairs: acc[i][j] (d=j*16+fr < 32) with acc[i][j+2] (d+32)
        const bool rope = (n0 + wc) < ROPE_END;   // uniform per wave-column
        #pragma unroll
        for (int j = 0; j < 2; ++j) {
            const int col1 = n0 + wc + j * 16 + fr;
            const int col2 = col1 + 32;
            const float b1 = bias[col1], b2 = bias[col2];
            const int d = j * 16 + fr;            // < 32
            #pragma unroll
            for (int i = 0; i < 2; ++i) {
                #pragma unroll
                for (int r = 0; r < 4; ++r) {
                    int row = m0 + wr + i * 16 + fq * 4 + r;
                    float v1 = acc[i][j][r] + b1;
                    float v2 = acc[i][j + 2][r] + b2;
                    if (rope) {
                        float c = cosT[row * 32 + d], s = sinT[row * 32 + d];
                        float w1 = v1 * c - v2 * s;
                        float w2 = v2 * c + v1 * s;
                        v1 = w1; v2 = w2;
                    }
                    C[(size_t)row * N + col1] = v1;
                    C[(size_t)row * N + col2] = v2;
                }
            }
        }
    } else {
        #pragma unroll
        for (int j = 0; j < 4; ++j) {
            int col = n0 + wc + j * 16 + fr;
            if (col < N) {
                float bv = bias[col];
                #pragma unroll
                for (int i = 0; i < 2; ++i) {
                    int row = m0 + wr + i * 16 + fq * 4;
                    #pragma unroll
                    for (int r = 0; r < 4; ++r)
                        C[(size_t)(row + r) * N + col] = acc[i][j][r] + bv;
                }
            }
        }
    }
}

// ---------------- MFMA sliding-window attention with sink ----------------
// block = (q-tile of 32, group g). rows = 8 heads x 32 q = 256; wave w owns rows
// [64w,64w+64) = heads {2w,2w+1}. Key slab: 160 keys from s0 = max(0,q0-127)
// covers every valid window. Single-tile softmax. QK^T: bf16 hi/lo 3-term MFMA.
// PV: f16 W (unnormalized e) x f16 V, normalize in epilogue. W aliases dead K.
__global__ __launch_bounds__(256, 1) void attn_mfma_kernel(
    const float* __restrict__ qkv, const float* __restrict__ sinks,
    ushort* __restrict__ attn_hi, ushort* __restrict__ attn_lo)
{
    __shared__ __align__(16) char smem[122880];
    ushort*   Khi = (ushort*)smem;                    // [160][64] bf16 (20480 B)
    ushort*   Klo = (ushort*)(smem + 20480);          // [160][64] bf16
    _Float16* Wl  = (_Float16*)smem;                  // [256][192] f16 (98304 B) aliases K
    _Float16* Vt  = (_Float16*)(smem + 98304);        // [64][192] f16 (24576 B)

    const int q0 = blockIdx.x * 32;
    const int g  = blockIdx.y;
    const int tid = threadIdx.x;
    const int w = tid >> 6, lane = tid & 63;
    const int fr = lane & 15, fq = lane >> 4;
    const int s0 = (q0 > 127) ? (q0 - 127) : 0;
    const int kmax = q0 + 32 - s0;                    // 32..159 staged keys

    for (int idx = tid; idx < 160 * 8; idx += 256) {
        int j = idx >> 3, c = idx & 7;
        float kv[8], vv[8];
        if (j < kmax) {
            const float* src = qkv + (size_t)(s0 + j) * QKV_DIM + ATTN_DIM + g * 64 + c * 8;
            *(float4*)&kv[0] = *(const float4*)src;
            *(float4*)&kv[4] = *(const float4*)(src + 4);
            const float* srcv = src + NKV * 64;
            *(float4*)&vv[0] = *(const float4*)srcv;
            *(float4*)&vv[4] = *(const float4*)(srcv + 4);
        } else {
            #pragma unroll
            for (int e = 0; e < 8; ++e) { kv[e] = 0.f; vv[e] = 0.f; }
        }
        sv8 hv, lv;
        #pragma unroll
        for (int e = 0; e < 8; ++e) {
            ushort h = f2bf(kv[e]);
            hv[e] = (short)h;
            lv[e] = (short)f2bf(kv[e] - bf2f(h));
        }
        int cs = c ^ (j & 7);
        *(sv8*)(Khi + j * 64 + cs * 8) = hv;
        *(sv8*)(Klo + j * 64 + cs * 8) = lv;
        int cj = j >> 3, jl = j & 7;
        #pragma unroll
        for (int e = 0; e < 8; ++e) {
            int d = c * 8 + e;
            int cp = (cj & 24) | ((cj & 7) ^ (d & 7));
            Vt[d * 192 + cp * 8 + jl] = (_Float16)vv[e];
        }
    }

    sv8 qhi[4][2], qlo[4][2];
    #pragma unroll
    for (int rf = 0; rf < 4; ++rf) {
        int hl = w * 2 + (rf >> 1);
        int qr = (rf & 1) * 16 + fr;
        const float* qrow = qkv + (size_t)(q0 + qr) * QKV_DIM + (g * 8 + hl) * 64;
        #pragma unroll
        for (int ks = 0; ks < 2; ++ks) {
            float v[8];
            *(float4*)&v[0] = *(const float4*)(qrow + ks * 32 + fq * 8);
            *(float4*)&v[4] = *(const float4*)(qrow + ks * 32 + fq * 8 + 4);
            #pragma unroll
            for (int e = 0; e < 8; ++e) {
                ushort h = f2bf(v[e]);
                qhi[rf][ks][e] = (short)h;
                qlo[rf][ks][e] = (short)f2bf(v[e] - bf2f(h));
            }
        }
    }

    __syncthreads();

    const int ncf = (kmax + 15) >> 4;
    f32x4 S[4][10] = {};
    #pragma unroll
    for (int ks = 0; ks < 2; ++ks) {
        #pragma unroll
        for (int cf = 0; cf < 10; ++cf) {
            if (cf < ncf) {
                int key = cf * 16 + fr;
                int cs = (ks * 4 + fq) ^ (key & 7);
                sv8 kh = *(const sv8*)(Khi + key * 64 + cs * 8);
                sv8 kl = *(const sv8*)(Klo + key * 64 + cs * 8);
                #pragma unroll
                for (int rf = 0; rf < 4; ++rf) {
                    S[rf][cf] = __builtin_amdgcn_mfma_f32_16x16x32_bf16(qhi[rf][ks], kh, S[rf][cf], 0, 0, 0);
                    S[rf][cf] = __builtin_amdgcn_mfma_f32_16x16x32_bf16(qlo[rf][ks], kh, S[rf][cf], 0, 0, 0);
                    S[rf][cf] = __builtin_amdgcn_mfma_f32_16x16x32_bf16(qhi[rf][ks], kl, S[rf][cf], 0, 0, 0);
                }
            }
        }
    }

    __syncthreads();

    float inv_s[4][4];
    #pragma unroll
    for (int rf = 0; rf < 4; ++rf) {
        float sink = sinks[g * 8 + w * 2 + (rf >> 1)];
        #pragma unroll
        for (int r = 0; r < 4; ++r) {
            int q = q0 + (rf & 1) * 16 + fq * 4 + r;
            float sv[10];
            float mx = sink;
            #pragma unroll
            for (int cf = 0; cf < 10; ++cf) {
                float v = S[rf][cf][r] * 0.125f;
                int kg = s0 + cf * 16 + fr;
                bool ok = (cf < ncf) && (kg <= q) && (kg + SW > q);
                v = ok ? v : -INFINITY;
                sv[cf] = v;
                mx = fmaxf(mx, v);
            }
            #pragma unroll
            for (int off = 1; off < 16; off <<= 1) mx = fmaxf(mx, __shfl_xor(mx, off));
            float sum = 0.f;
            #pragma unroll
            for (int cf = 0; cf < 10; ++cf) {
                float e = __expf(sv[cf] - mx);
                sv[cf] = e;
                sum += e;
            }
            #pragma unroll
            for (int off = 1; off < 16; off <<= 1) sum += __shfl_xor(sum, off);
            sum += __expf(sink - mx);
            inv_s[rf][r] = 1.f / sum;
            int row = w * 64 + rf * 16 + fq * 4 + r;
            #pragma unroll
            for (int cf = 0; cf < 10; ++cf) {
                if (cf < ncf) {
                    int key = cf * 16 + fr;
                    int cj = key >> 3;
                    int cp = (cj & 24) | ((cj & 7) ^ (row & 7));
                    Wl[row * 192 + cp * 8 + (key & 7)] = (_Float16)sv[cf];
                }
            }
        }
    }

    __syncthreads();

    const int nks = (kmax + 31) >> 5;
    f32x4 O[4][4] = {};
    #pragma unroll
    for (int ks = 0; ks < 5; ++ks) {
        if (ks < nks) {
            h8 a[4], b[4];
            int cj = ks * 4 + fq;
            #pragma unroll
            for (int rf = 0; rf < 4; ++rf) {
                int row = w * 64 + rf * 16 + fr;
                int cp = (cj & 24) | ((cj & 7) ^ (row & 7));
                a[rf] = *(const h8*)(Wl + row * 192 + cp * 8);
            }
            #pragma unroll
            for (int df = 0; df < 4; ++df) {
                int d = df * 16 + fr;
                int cp = (cj & 24) | ((cj & 7) ^ (d & 7));
                b[df] = *(const h8*)(Vt + d * 192 + cp * 8);
            }
            #pragma unroll
            for (int rf = 0; rf < 4; ++rf)
                #pragma unroll
                for (int df = 0; df < 4; ++df)
                    O[rf][df] = __builtin_amdgcn_mfma_f32_16x16x32_f16(a[rf], b[df], O[rf][df], 0, 0, 0);
        }
    }

    #pragma unroll
    for (int rf = 0; rf < 4; ++rf) {
        int H = g * 8 + w * 2 + (rf >> 1);
        #pragma unroll
        for (int df = 0; df < 4; ++df) {
            int d = df * 16 + fr;
            #pragma unroll
            for (int r = 0; r < 4; ++r) {
                int qr = (rf & 1) * 16 + fq * 4 + r;
                float v = O[rf][df][r] * inv_s[rf][r];
                size_t addr = (size_t)(q0 + qr) * ATTN_DIM + H * 64 + d;
                ushort h16 = f2bf(v);
                attn_hi[addr] = h16;
                attn_lo[addr] = f2bf(v - bf2f(h16));
            }
        }
    }
}

extern "C" void kernel_launch(void* const* d_in, const int* in_sizes, int n_in,
                              void* d_out, int out_size, void* d_ws, size_t ws_size,
                              hipStream_t stream) {
    const float* x          = (const float*)d_in[0];
    const float* norm_scale = (const float*)d_in[1];
    const float* qkv_w      = (const float*)d_in[2];
    const float* qkv_b      = (const float*)d_in[3];
    const float* out_w      = (const float*)d_in[4];
    const float* out_b      = (const float*)d_in[5];
    const float* sinks      = (const float*)d_in[6];
    float* out = (float*)d_out;

    char* p = (char*)d_ws;
    auto alloc = [&](size_t bytes) { char* r = p; p += (bytes + 255) & ~(size_t)255; return r; };
    const size_t W_ELEMS  = (size_t)QKV_DIM * HIDDEN;
    const size_t W_ELEMS2 = (size_t)OW_NPAD * ATTN_DIM;
    const size_t W_MAX = W_ELEMS > W_ELEMS2 ? W_ELEMS : W_ELEMS2;
    ushort* w_hi  = (ushort*)alloc(W_MAX * 2);
    ushort* w_lo  = (ushort*)alloc(W_MAX * 2);
    ushort* ab_hi  = (ushort*)alloc((size_t)T_TOK * ATTN_DIM * 2);
    ushort* ab_lo  = (ushort*)alloc((size_t)T_TOK * ATTN_DIM * 2);
    float*  qkv_buf = (float*)alloc((size_t)T_TOK * QKV_DIM * 4);
    float*  cosT   = (float*)alloc((size_t)T_TOK * 32 * 4);
    float*  sinT   = (float*)alloc((size_t)T_TOK * 32 * 4);

    rope_table_kernel<<<(T_TOK * 32) / 256, 256, 0, stream>>>(cosT, sinT);

    long n_qw = (long)QKV_DIM * HIDDEN;
    split_kernel<<<(int)(n_qw / 4 / 256), 256, 0, stream>>>(qkv_w, w_hi, w_lo, n_qw, n_qw);

    rmsnorm_kernel<<<T_TOK, 256, 0, stream>>>(x, norm_scale, ab_hi, ab_lo);

    // GEMM1 (RoPE fused): grid = 16 m-blocks x 40 n-blocks = 640 (% 8 == 0)
    gemm_mfma_split<true><<<(T_TOK / 64) * (QKV_DIM / 128), 256, 0, stream>>>(
        ab_hi, ab_lo, w_hi, w_lo, qkv_b, qkv_buf, cosT, sinT, QKV_DIM, HIDDEN);

    attn_mfma_kernel<<<dim3(T_TOK / 32, NKV), 256, 0, stream>>>(qkv_buf, sinks, ab_hi, ab_lo);

    long n_ow_src = (long)HIDDEN * ATTN_DIM;
    long n_ow_dst = (long)OW_NPAD * ATTN_DIM;
    split_kernel<<<(int)(n_ow_dst / 4 / 256), 256, 0, stream>>>(out_w, w_hi, w_lo, n_ow_src, n_ow_dst);

    // GEMM2: grid = 16 x 23 = 368 (% 8 == 0)
    gemm_mfma_split<false><<<(T_TOK / 64) * (OW_NPAD / 128), 256, 0, stream>>>(
        ab_hi, ab_lo, w_hi, w_lo, out_b, out, nullptr, nullptr, HIDDEN, ATTN_DIM);
}

// Round 8
// 390.333 us; speedup vs baseline: 4.6413x; 1.0227x over previous
//
#include <hip/hip_runtime.h>
#include <hip/hip_bf16.h>
#include <math.h>

#define T_TOK 1024
#define HIDDEN 2880
#define HD 64
#define NH 64
#define NKV 8
#define SW 128
#define QKV_DIM 5120   // HD*(NH+2*NKV)
#define ATTN_DIM 4096  // NH*HD
#define OW_NPAD 2944   // 2880 padded to multiple of 128
#define ROPE_END 4608  // cols < this (q+k heads) get RoPE in GEMM1 epilogue
#define QBLK 16

typedef __attribute__((ext_vector_type(8))) short sv8;       // 8 x bf16 fragment
typedef __attribute__((ext_vector_type(8))) _Float16 h8;     // 8 x f16 fragment
typedef __attribute__((ext_vector_type(4))) float f32x4;     // MFMA accumulator

__device__ __forceinline__ ushort f2bf(float f) {
    union { float f; unsigned u; } v; v.f = f;
    unsigned r = v.u + 0x7fffu + ((v.u >> 16) & 1u);   // round-to-nearest-even
    return (ushort)(r >> 16);
}
__device__ __forceinline__ float bf2f(ushort h) {
    union { unsigned u; float f; } v; v.u = ((unsigned)h) << 16;
    return v.f;
}
__device__ __forceinline__ ushort f2h(float f) {
    union { _Float16 h; ushort u; } v; v.h = (_Float16)f; return v.u;
}
__device__ __forceinline__ void gload16(const ushort* g, ushort* l) {
    __builtin_amdgcn_global_load_lds(
        (const __attribute__((address_space(1))) unsigned int*)g,
        (__attribute__((address_space(3))) unsigned int*)l, 16, 0, 0);
}

// ---------------- RoPE table (1024 x 32) ----------------
__global__ void rope_table_kernel(float* __restrict__ cosT, float* __restrict__ sinT) {
    int gid = blockIdx.x * 256 + threadIdx.x;   // < 1024*32
    int i = gid & 31;
    int t = gid >> 5;
    const double d_half = 32.0;
    double freq = pow(150000.0, (double)i / 32.0);
    double lowd  = d_half * log(4096.0 / (32.0 * 2.0 * M_PI)) / log(150000.0);
    double highd = d_half * log(4096.0 / (2.0 * M_PI)) / log(150000.0);
    double ramp = ((double)i - lowd) / (highd - lowd);
    ramp = fmin(fmax(ramp, 0.0), 1.0);
    double m = 1.0 - ramp;
    double inv_freq = (1.0 / (32.0 * freq)) * (1.0 - m) + (1.0 / freq) * m;
    float phase = (float)t * (float)inv_freq;    // fp32 multiply like numpy
    double conc = 0.1 * log(32.0) + 1.0;
    cosT[gid] = (float)(cos((double)phase) * conc);
    sinT[gid] = (float)(sin((double)phase) * conc);
}

// ---------------- split fp32 -> bf16 hi/lo (generic, zero-pads dst) ----------------
__global__ __launch_bounds__(256) void split_kernel(const float* __restrict__ X,
                                                    ushort* __restrict__ hi,
                                                    ushort* __restrict__ lo,
                                                    long n_src, long n_dst) {
    long i = ((long)blockIdx.x * 256 + threadIdx.x) * 4;
    if (i >= n_dst) return;
    float4 v = make_float4(0.f, 0.f, 0.f, 0.f);
    if (i < n_src) v = *(const float4*)(X + i);
    ushort4 h, l;
    h.x = f2bf(v.x); l.x = f2bf(v.x - bf2f(h.x));
    h.y = f2bf(v.y); l.y = f2bf(v.y - bf2f(h.y));
    h.z = f2bf(v.z); l.z = f2bf(v.z - bf2f(h.z));
    h.w = f2bf(v.w); l.w = f2bf(v.w - bf2f(h.w));
    *(ushort4*)(hi + i) = h;
    *(ushort4*)(lo + i) = l;
}

// ---------------- RMSNorm -> split bf16 hi/lo ----------------
__global__ __launch_bounds__(256) void rmsnorm_kernel(const float* __restrict__ x,
                                                      const float* __restrict__ scale,
                                                      ushort* __restrict__ t_hi,
                                                      ushort* __restrict__ t_lo) {
    const int row = blockIdx.x;
    const int tid = threadIdx.x;
    const float4* xr = (const float4*)(x + (size_t)row * HIDDEN);
    float4 v[3];
    float ss = 0.f;
    int cnt = 0;
    for (int i = tid; i < HIDDEN / 4; i += 256) {
        float4 a = xr[i];
        v[cnt++] = a;
        ss += a.x * a.x + a.y * a.y + a.z * a.z + a.w * a.w;
    }
    #pragma unroll
    for (int off = 32; off; off >>= 1) ss += __shfl_xor(ss, off);
    __shared__ float red[4];
    if ((tid & 63) == 0) red[tid >> 6] = ss;
    __syncthreads();
    float total = red[0] + red[1] + red[2] + red[3];
    float inv = rsqrtf(total / (float)HIDDEN + 1e-5f);
    const float4* sc = (const float4*)scale;
    cnt = 0;
    for (int i = tid; i < HIDDEN / 4; i += 256) {
        float4 a = v[cnt++];
        float4 s4 = sc[i];
        float4 o;
        o.x = a.x * inv * s4.x; o.y = a.y * inv * s4.y;
        o.z = a.z * inv * s4.z; o.w = a.w * inv * s4.w;
        ushort4 h, l;
        h.x = f2bf(o.x); l.x = f2bf(o.x - bf2f(h.x));
        h.y = f2bf(o.y); l.y = f2bf(o.y - bf2f(h.y));
        h.z = f2bf(o.z); l.z = f2bf(o.z - bf2f(h.z));
        h.w = f2bf(o.w); l.w = f2bf(o.w - bf2f(h.w));
        *(ushort4*)(t_hi + (size_t)row * HIDDEN + i * 4) = h;
        *(ushort4*)(t_lo + (size_t)row * HIDDEN + i * 4) = l;
    }
}

// ---------------- split-bf16 MFMA GEMM: C[M][N] = A·B^T + bias ----------------
// Tile 64x128, BK=64, 4 waves, LDS 48 KB, XCD-swizzled 1D grid (m-major/XCD).
// ROPE epilogue (GEMM1): q cols -> rope + fp32 C; k cols -> rope + bf16 hi/lo
// khi/klo [g][t][64]; v cols -> f16 vt [g*64+d][t] (transposed).
template <bool ROPE>
__global__ __launch_bounds__(256, 2) void gemm_mfma_split(
    const ushort* __restrict__ Ahi, const ushort* __restrict__ Alo,
    const ushort* __restrict__ Bhi, const ushort* __restrict__ Blo,
    const float* __restrict__ bias, float* __restrict__ C,
    const float* __restrict__ cosT, const float* __restrict__ sinT,
    ushort* __restrict__ khi, ushort* __restrict__ klo, ushort* __restrict__ vt,
    const int N, const int K)
{
    __shared__ __align__(16) ushort sAhi[64 * 64];
    __shared__ __align__(16) ushort sAlo[64 * 64];
    __shared__ __align__(16) ushort sBhi[128 * 64];
    __shared__ __align__(16) ushort sBlo[128 * 64];

    const int tid = threadIdx.x;
    const int cpx = gridDim.x >> 3;
    const int L = blockIdx.x;
    const int lin = (L & 7) * cpx + (L >> 3);
    const int m0 = (lin & 15) * 64;
    const int n0 = (lin >> 4) * 128;

    const int w = tid >> 6, lane = tid & 63;
    const int wr = (w >> 1) * 32, wc = (w & 1) * 64;
    const int fr = lane & 15, fq = lane >> 4;

    int offA[2], loffA[2], offB[4], loffB[4];
    #pragma unroll
    for (int q = 0; q < 2; ++q) {
        int c = tid + q * 256;
        int row = c >> 3, pc = c & 7;
        int gcol = (pc ^ (row & 7)) * 8;
        offA[q] = (m0 + row) * K + gcol;
        loffA[q] = c * 8;
    }
    #pragma unroll
    for (int q = 0; q < 4; ++q) {
        int c = tid + q * 256;
        int row = c >> 3, pc = c & 7;
        int gcol = (pc ^ (row & 7)) * 8;
        offB[q] = (n0 + row) * K + gcol;
        loffB[q] = c * 8;
    }

    f32x4 acc[2][4] = {};

    for (int k0 = 0; k0 < K; k0 += 64) {
        #pragma unroll
        for (int q = 0; q < 2; ++q) {
            gload16(Ahi + offA[q] + k0, sAhi + loffA[q]);
            gload16(Alo + offA[q] + k0, sAlo + loffA[q]);
        }
        #pragma unroll
        for (int q = 0; q < 4; ++q) {
            gload16(Bhi + offB[q] + k0, sBhi + loffB[q]);
            gload16(Blo + offB[q] + k0, sBlo + loffB[q]);
        }
        __syncthreads();
        #pragma unroll
        for (int ks = 0; ks < 2; ++ks) {
            sv8 ahi[2], alo[2], bhi[4], blo[4];
            const int cx = ((ks * 4 + fq) ^ (fr & 7)) * 8;
            #pragma unroll
            for (int i = 0; i < 2; ++i) {
                int ra = (wr + i * 16 + fr) * 64 + cx;
                ahi[i] = *(const sv8*)(sAhi + ra);
                alo[i] = *(const sv8*)(sAlo + ra);
            }
            #pragma unroll
            for (int j = 0; j < 4; ++j) {
                int rb = (wc + j * 16 + fr) * 64 + cx;
                bhi[j] = *(const sv8*)(sBhi + rb);
                blo[j] = *(const sv8*)(sBlo + rb);
            }
            #pragma unroll
            for (int i = 0; i < 2; ++i)
                #pragma unroll
                for (int j = 0; j < 4; ++j) {
                    acc[i][j] = __builtin_amdgcn_mfma_f32_16x16x32_bf16(ahi[i], bhi[j], acc[i][j], 0, 0, 0);
                    acc[i][j] = __builtin_amdgcn_mfma_f32_16x16x32_bf16(ahi[i], blo[j], acc[i][j], 0, 0, 0);
                    acc[i][j] = __builtin_amdgcn_mfma_f32_16x16x32_bf16(alo[i], bhi[j], acc[i][j], 0, 0, 0);
                }
        }
        __syncthreads();
    }

    // C/D layout: col = lane&15, row = (lane>>4)*4 + reg
    if (ROPE) {
        const int colbase = n0 + wc;   // wave-uniform; head boundaries align (64)
        if (colbase < ATTN_DIM) {
            // q heads: rope, fp32 store to qkv_buf
            #pragma unroll
            for (int j = 0; j < 2; ++j) {
                const int col1 = colbase + j * 16 + fr;
                const float b1 = bias[col1], b2 = bias[col1 + 32];
                const int d = j * 16 + fr;
                #pragma unroll
                for (int i = 0; i < 2; ++i) {
                    #pragma unroll
                    for (int r = 0; r < 4; ++r) {
                        int row = m0 + wr + i * 16 + fq * 4 + r;
                        float v1 = acc[i][j][r] + b1;
                        float v2 = acc[i][j + 2][r] + b2;
                        float c = cosT[row * 32 + d], s = sinT[row * 32 + d];
                        float w1 = v1 * c - v2 * s;
                        float w2 = v2 * c + v1 * s;
                        C[(size_t)row * N + col1] = w1;
                        C[(size_t)row * N + col1 + 32] = w2;
                    }
                }
            }
        } else if (colbase < ROPE_END) {
            // k heads: rope, bf16 hi/lo store to khi/klo [g][t][64]
            const int gk = (colbase - ATTN_DIM) >> 6;
            #pragma unroll
            for (int j = 0; j < 2; ++j) {
                const int d1 = j * 16 + fr;
                const float b1 = bias[colbase + d1], b2 = bias[colbase + d1 + 32];
                #pragma unroll
                for (int i = 0; i < 2; ++i) {
                    #pragma unroll
                    for (int r = 0; r < 4; ++r) {
                        int row = m0 + wr + i * 16 + fq * 4 + r;
                        float v1 = acc[i][j][r] + b1;
                        float v2 = acc[i][j + 2][r] + b2;
                        float c = cosT[row * 32 + d1], s = sinT[row * 32 + d1];
                        float w1 = v1 * c - v2 * s;
                        float w2 = v2 * c + v1 * s;
                        size_t base = ((size_t)(gk << 10) + row) << 6;
                        ushort h1 = f2bf(w1), h2 = f2bf(w2);
                        khi[base + d1] = h1;       klo[base + d1] = f2bf(w1 - bf2f(h1));
                        khi[base + d1 + 32] = h2;  klo[base + d1 + 32] = f2bf(w2 - bf2f(h2));
                    }
                }
            }
        } else {
            // v heads: f16 transposed store vt[col-4608][t]
            const int cb = colbase - ROPE_END;
            #pragma unroll
            for (int j = 0; j < 4; ++j) {
                const int col = cb + j * 16 + fr;
                const float bv = bias[colbase + j * 16 + fr];
                #pragma unroll
                for (int i = 0; i < 2; ++i) {
                    int row = m0 + wr + i * 16 + fq * 4;
                    ushort4 st;
                    st.x = f2h(acc[i][j][0] + bv);
                    st.y = f2h(acc[i][j][1] + bv);
                    st.z = f2h(acc[i][j][2] + bv);
                    st.w = f2h(acc[i][j][3] + bv);
                    *(ushort4*)(vt + ((size_t)col << 10) + row) = st;
                }
            }
        }
    } else {
        #pragma unroll
        for (int j = 0; j < 4; ++j) {
            int col = n0 + wc + j * 16 + fr;
            if (col < N) {
                float bv = bias[col];
                #pragma unroll
                for (int i = 0; i < 2; ++i) {
                    int row = m0 + wr + i * 16 + fq * 4;
                    #pragma unroll
                    for (int r = 0; r < 4; ++r)
                        C[(size_t)(row + r) * N + col] = acc[i][j][r] + bv;
                }
            }
        }
    }
}

// ---------------- MFMA sliding-window attention with sink ----------------
// block = (q-tile of 16, group g): 512 blocks, 72 KB LDS -> 2 blocks/CU.
// 4 waves; wave w owns heads {2w, 2w+1} x 16 q rows. Key slab from s0a
// (16B-aligned) <= 144 keys covers all windows. K staged via gload16 from
// pre-split khi/klo (GEMM1 epilogue); Vt reg-staged f16. W/Vt zero-padded to
// nks*32 keys so PV never reads garbage.
__global__ __launch_bounds__(256, 2) void attn_mfma_kernel(
    const float* __restrict__ qkv, const ushort* __restrict__ khi,
    const ushort* __restrict__ klo, const ushort* __restrict__ vt,
    const float* __restrict__ sinks,
    ushort* __restrict__ attn_hi, ushort* __restrict__ attn_lo)
{
    __shared__ __align__(16) char smem[73728];
    ushort*   Khi = (ushort*)smem;                    // [144][64] bf16 (18432 B)
    ushort*   Klo = (ushort*)(smem + 18432);          // [144][64] bf16
    _Float16* Wl  = (_Float16*)smem;                  // [128][192] f16 (49152 B) aliases K
    _Float16* Vt  = (_Float16*)(smem + 49152);        // [64][192] f16 (24576 B)

    const int q0 = blockIdx.x * QBLK;
    const int g  = blockIdx.y;
    const int tid = threadIdx.x;
    const int w = tid >> 6, lane = tid & 63;
    const int fr = lane & 15, fq = lane >> 4;
    const int s0 = (q0 > 127) ? (q0 - 127) : 0;
    const int s0a = s0 & ~7;                          // 16B-aligned slab start
    const int kmax = q0 + QBLK - s0a;                 // multiple of 8; <= 144
    const int ncf = kmax >> 4;                        // exact 16-key frags
    const int nks = (kmax + 31) >> 5;                 // 32-key PV steps
    const int kzend = nks << 5;                       // zero-padded extent (<=160)

    // ---- stage K via gload16 (lane-linear dest, source pre-swizzled) ----
    for (int idx = tid; idx < 144 * 8; idx += 256) {
        if ((idx >> 3) < kmax) {                      // wave-uniform (kmax%8==0)
            int j = idx >> 3, pc = idx & 7;
            int src = (((g << 10) + s0a + j) << 6) + ((pc ^ (j & 7)) << 3);
            gload16(khi + src, Khi + idx * 8);
            gload16(klo + src, Klo + idx * 8);
        }
    }
    // ---- stage Vt f16 (reg-staged, swizzled ds_write; zero beyond kmax) ----
    for (int idx = tid; idx < 64 * 20; idx += 256) {
        int d = idx / 20, cj = idx % 20;
        int4 vdat = make_int4(0, 0, 0, 0);
        if ((cj << 3) < kmax)
            vdat = *(const int4*)(vt + (((size_t)(g << 6) + d) << 10) + s0a + (cj << 3));
        int cp = (cj & 24) | ((cj & 7) ^ (d & 7));
        *(int4*)(Vt + d * 192 + cp * 8) = vdat;
    }

    // ---- Q fragments in registers (load fp32, split hi/lo) ----
    sv8 qhi[2][2], qlo[2][2];
    #pragma unroll
    for (int rf = 0; rf < 2; ++rf) {
        const float* qrow = qkv + (size_t)(q0 + fr) * QKV_DIM + (g * 8 + w * 2 + rf) * 64;
        #pragma unroll
        for (int ks = 0; ks < 2; ++ks) {
            float v[8];
            *(float4*)&v[0] = *(const float4*)(qrow + ks * 32 + fq * 8);
            *(float4*)&v[4] = *(const float4*)(qrow + ks * 32 + fq * 8 + 4);
            #pragma unroll
            for (int e = 0; e < 8; ++e) {
                ushort h = f2bf(v[e]);
                qhi[rf][ks][e] = (short)h;
                qlo[rf][ks][e] = (short)f2bf(v[e] - bf2f(h));
            }
        }
    }

    __syncthreads();

    // ---- QK^T: S[2 head-frags][<=9 key-frags], 3-term split ----
    f32x4 S[2][9] = {};
    #pragma unroll
    for (int ks = 0; ks < 2; ++ks) {
        #pragma unroll
        for (int cf = 0; cf < 9; ++cf) {
            if (cf < ncf) {
                int key = cf * 16 + fr;
                int cs = ((ks * 4 + fq) ^ (key & 7)) * 8;
                sv8 kh = *(const sv8*)(Khi + key * 64 + cs);
                sv8 kl = *(const sv8*)(Klo + key * 64 + cs);
                #pragma unroll
                for (int rf = 0; rf < 2; ++rf) {
                    S[rf][cf] = __builtin_amdgcn_mfma_f32_16x16x32_bf16(qhi[rf][ks], kh, S[rf][cf], 0, 0, 0);
                    S[rf][cf] = __builtin_amdgcn_mfma_f32_16x16x32_bf16(qlo[rf][ks], kh, S[rf][cf], 0, 0, 0);
                    S[rf][cf] = __builtin_amdgcn_mfma_f32_16x16x32_bf16(qhi[rf][ks], kl, S[rf][cf], 0, 0, 0);
                }
            }
        }
    }

    __syncthreads();   // K dead; W may overwrite

    // ---- softmax (16-lane shfl reduce) -> unnormalized e to W (f16) ----
    float inv_s[2][4];
    #pragma unroll
    for (int rf = 0; rf < 2; ++rf) {
        float sink = sinks[g * 8 + w * 2 + rf];
        #pragma unroll
        for (int r = 0; r < 4; ++r) {
            int q = q0 + fq * 4 + r;
            float sv[10] = {};
            float mx = sink;
            #pragma unroll
            for (int cf = 0; cf < 9; ++cf) {
                float v = S[rf][cf][r] * 0.125f;
                int kg = s0a + cf * 16 + fr;
                bool ok = (cf < ncf) && (kg <= q) && (kg + SW > q);
                v = ok ? v : -INFINITY;
                sv[cf] = v;
                mx = fmaxf(mx, v);
            }
            #pragma unroll
            for (int off = 1; off < 16; off <<= 1) mx = fmaxf(mx, __shfl_xor(mx, off));
            float sum = 0.f;
            #pragma unroll
            for (int cf = 0; cf < 9; ++cf) {
                float e = (cf < ncf) ? __expf(sv[cf] - mx) : 0.f;
                sv[cf] = e;
                sum += e;
            }
            #pragma unroll
            for (int off = 1; off < 16; off <<= 1) sum += __shfl_xor(sum, off);
            sum += __expf(sink - mx);
            inv_s[rf][r] = 1.f / sum;
            int row = w * 32 + rf * 16 + fq * 4 + r;
            #pragma unroll
            for (int cf = 0; cf < 10; ++cf) {
                int key = cf * 16 + fr;
                if (key < kzend) {
                    int cj = key >> 3;
                    int cp = (cj & 24) | ((cj & 7) ^ (row & 7));
                    Wl[row * 192 + cp * 8 + (key & 7)] = (_Float16)sv[cf];
                }
            }
        }
    }

    __syncthreads();

    // ---- PV: O[32 rows][64 d] = W · V (f16 MFMA) ----
    f32x4 O[2][4] = {};
    #pragma unroll
    for (int ks = 0; ks < 5; ++ks) {
        if (ks < nks) {
            h8 a[2], b[4];
            int cj = ks * 4 + fq;
            #pragma unroll
            for (int rf = 0; rf < 2; ++rf) {
                int row = w * 32 + rf * 16 + fr;
                int cp = (cj & 24) | ((cj & 7) ^ (row & 7));
                a[rf] = *(const h8*)(Wl + row * 192 + cp * 8);
            }
            #pragma unroll
            for (int df = 0; df < 4; ++df) {
                int d = df * 16 + fr;
                int cp = (cj & 24) | ((cj & 7) ^ (d & 7));
                b[df] = *(const h8*)(Vt + d * 192 + cp * 8);
            }
            #pragma unroll
            for (int rf = 0; rf < 2; ++rf)
                #pragma unroll
                for (int df = 0; df < 4; ++df)
                    O[rf][df] = __builtin_amdgcn_mfma_f32_16x16x32_f16(a[rf], b[df], O[rf][df], 0, 0, 0);
        }
    }

    // ---- epilogue: normalize, split hi/lo bf16 ----
    #pragma unroll
    for (int rf = 0; rf < 2; ++rf) {
        int H = g * 8 + w * 2 + rf;
        #pragma unroll
        for (int df = 0; df < 4; ++df) {
            int d = df * 16 + fr;
            #pragma unroll
            for (int r = 0; r < 4; ++r) {
                float v = O[rf][df][r] * inv_s[rf][r];
                size_t addr = (size_t)(q0 + fq * 4 + r) * ATTN_DIM + H * 64 + d;
                ushort h16 = f2bf(v);
                attn_hi[addr] = h16;
                attn_lo[addr] = f2bf(v - bf2f(h16));
            }
        }
    }
}

extern "C" void kernel_launch(void* const* d_in, const int* in_sizes, int n_in,
                              void* d_out, int out_size, void* d_ws, size_t ws_size,
                              hipStream_t stream) {
    const float* x          = (const float*)d_in[0];
    const float* norm_scale = (const float*)d_in[1];
    const float* qkv_w      = (const float*)d_in[2];
    const float* qkv_b      = (const float*)d_in[3];
    const float* out_w      = (const float*)d_in[4];
    const float* out_b      = (const float*)d_in[5];
    const float* sinks      = (const float*)d_in[6];
    float* out = (float*)d_out;

    char* p = (char*)d_ws;
    auto alloc = [&](size_t bytes) { char* r = p; p += (bytes + 255) & ~(size_t)255; return r; };
    const size_t W_ELEMS  = (size_t)QKV_DIM * HIDDEN;
    const size_t W_ELEMS2 = (size_t)OW_NPAD * ATTN_DIM;
    const size_t W_MAX = W_ELEMS > W_ELEMS2 ? W_ELEMS : W_ELEMS2;
    ushort* w_hi  = (ushort*)alloc(W_MAX * 2);
    ushort* w_lo  = (ushort*)alloc(W_MAX * 2);
    ushort* ab_hi  = (ushort*)alloc((size_t)T_TOK * ATTN_DIM * 2);
    ushort* ab_lo  = (ushort*)alloc((size_t)T_TOK * ATTN_DIM * 2);
    float*  qkv_buf = (float*)alloc((size_t)T_TOK * QKV_DIM * 4);
    ushort* khi = (ushort*)alloc((size_t)NKV * T_TOK * HD * 2);
    ushort* klo = (ushort*)alloc((size_t)NKV * T_TOK * HD * 2);
    ushort* vt  = (ushort*)alloc((size_t)NKV * HD * T_TOK * 2);
    float*  cosT = (float*)alloc((size_t)T_TOK * 32 * 4);
    float*  sinT = (float*)alloc((size_t)T_TOK * 32 * 4);

    rope_table_kernel<<<(T_TOK * 32) / 256, 256, 0, stream>>>(cosT, sinT);

    long n_qw = (long)QKV_DIM * HIDDEN;
    split_kernel<<<(int)(n_qw / 4 / 256), 256, 0, stream>>>(qkv_w, w_hi, w_lo, n_qw, n_qw);

    rmsnorm_kernel<<<T_TOK, 256, 0, stream>>>(x, norm_scale, ab_hi, ab_lo);

    // GEMM1 (RoPE + k/v conversion fused): grid = 16 x 40 = 640
    gemm_mfma_split<true><<<(T_TOK / 64) * (QKV_DIM / 128), 256, 0, stream>>>(
        ab_hi, ab_lo, w_hi, w_lo, qkv_b, qkv_buf, cosT, sinT, khi, klo, vt,
        QKV_DIM, HIDDEN);

    attn_mfma_kernel<<<dim3(T_TOK / QBLK, NKV), 256, 0, stream>>>(
        qkv_buf, khi, klo, vt, sinks, ab_hi, ab_lo);

    long n_ow_src = (long)HIDDEN * ATTN_DIM;
    long n_ow_dst = (long)OW_NPAD * ATTN_DIM;
    split_kernel<<<(int)(n_ow_dst / 4 / 256), 256, 0, stream>>>(out_w, w_hi, w_lo, n_ow_src, n_ow_dst);

    // GEMM2: grid = 16 x 23 = 368
    gemm_mfma_split<false><<<(T_TOK / 64) * (OW_NPAD / 128), 256, 0, stream>>>(
        ab_hi, ab_lo, w_hi, w_lo, out_b, out, nullptr, nullptr,
        nullptr, nullptr, nullptr, HIDDEN, ATTN_DIM);
}